// Round 1
// baseline (1180.119 us; speedup 1.0000x reference)
//
#include <hip/hip_runtime.h>

#define HW 65536  // 256*256

typedef __bf16 bf16x8 __attribute__((ext_vector_type(8)));
typedef float f32x4 __attribute__((ext_vector_type(4)));

__device__ __forceinline__ float b2f(unsigned short u) {
    return __uint_as_float(((unsigned)u) << 16);
}
__device__ __forceinline__ unsigned short f2bu(float f) {
    unsigned u = __float_as_uint(f);
    return (unsigned short)((u + 0x7FFFu + ((u >> 16) & 1u)) >> 16);
}

// ---------------------------------------------------------------------------
// K0: fold 6 depthwise kernels -> combined 21-tap h + 21-tap v per tensor,
// and sum the 6 biases per tensor. wcomb layout: wh1|wv1|wh2|wv2, each 64*21.
__global__ void k_prep(const float* k11, const float* k12, const float* k13,
                       const float* k14, const float* k15, const float* k16,
                       const float* k21, const float* k22, const float* k23,
                       const float* k24, const float* k25, const float* k26,
                       const float* bdw, float* wcomb, float* bias) {
    int c = threadIdx.x;
    if (c >= 64) return;
    float* wh1 = wcomb;
    float* wv1 = wcomb + 1344;
    float* wh2 = wcomb + 2688;
    float* wv2 = wcomb + 4032;
    for (int j = 0; j < 21; j++) {
        wh1[c*21+j] = k13[c*21+j];
        wv1[c*21+j] = k16[c*21+j];
        wh2[c*21+j] = k23[c*21+j];
        wv2[c*21+j] = k26[c*21+j];
    }
    for (int j = 0; j < 11; j++) {
        wh1[c*21+j+5] += k12[c*11+j];
        wv1[c*21+j+5] += k15[c*11+j];
        wh2[c*21+j+5] += k22[c*11+j];
        wv2[c*21+j+5] += k25[c*11+j];
    }
    for (int j = 0; j < 7; j++) {
        wh1[c*21+j+7] += k11[c*7+j];
        wv1[c*21+j+7] += k14[c*7+j];
        wh2[c*21+j+7] += k21[c*7+j];
        wv2[c*21+j+7] += k24[c*7+j];
    }
    float s1 = 0.f, s2 = 0.f;
    for (int i = 0; i < 6; i++) { s1 += bdw[i*64+c]; s2 += bdw[(6+i)*64+c]; }
    bias[c] = s1; bias[64+c] = s2;
}

// ---------------------------------------------------------------------------
// K1: per-pixel LayerNorm over 64 channels, fp32 in -> bf16 out (NCHW).
__global__ __launch_bounds__(256) void k_ln(
        const float* __restrict__ x1, const float* __restrict__ x2,
        const float* __restrict__ w1, const float* __restrict__ b1,
        const float* __restrict__ w2, const float* __restrict__ b2,
        unsigned short* __restrict__ o1, unsigned short* __restrict__ o2) {
    int which = blockIdx.y;
    const float* x  = which ? x2 : x1;
    const float* lw = which ? w2 : w1;
    const float* lb = which ? b2 : b1;
    unsigned short* o = which ? o2 : o1;
    int p = blockIdx.x * 256 + threadIdx.x;   // 0..262143
    int b = p >> 16, hw = p & (HW - 1);
    size_t base = (size_t)b * 64 * HW + hw;
    float v[64];
    float s = 0.f;
    #pragma unroll
    for (int c = 0; c < 64; c++) { v[c] = x[base + (size_t)c * HW]; s += v[c]; }
    float mu = s * 0.015625f;
    float s2 = 0.f;
    #pragma unroll
    for (int c = 0; c < 64; c++) { float d = v[c] - mu; s2 += d * d; }
    float rstd = rsqrtf(s2 * 0.015625f + 1e-5f);
    #pragma unroll
    for (int c = 0; c < 64; c++)
        o[base + (size_t)c * HW] = f2bu((v[c] - mu) * rstd * lw[c] + lb[c]);
}

// ---------------------------------------------------------------------------
// K2: combined depthwise conv (21-tap h + 21-tap v + bias). One block per
// (tensor,b,c,h) row of 256; weights uniform per block (scalar loads).
__global__ __launch_bounds__(256) void k_dw(
        const unsigned short* __restrict__ in1, const unsigned short* __restrict__ in2,
        const float* __restrict__ wcomb, const float* __restrict__ bias,
        unsigned short* __restrict__ o1, unsigned short* __restrict__ o2) {
    int which = blockIdx.y;
    const unsigned short* in = which ? in2 : in1;
    unsigned short* o = which ? o2 : o1;
    const float* wh = wcomb + which * 2688;
    const float* wv = wh + 1344;
    int id = blockIdx.x;               // (b*64+c)*256 + h
    int h = id & 255, bc = id >> 8, c = bc & 63;
    int w = threadIdx.x;
    const unsigned short* base = in + (size_t)bc * HW;
    float acc = bias[which * 64 + c];
    const float* whc = wh + c * 21;
    const float* wvc = wv + c * 21;
    const unsigned short* row = base + h * 256;
    #pragma unroll
    for (int j = 0; j < 21; j++) {
        int xx = w + j - 10;
        if ((unsigned)xx < 256u) acc += whc[j] * b2f(row[xx]);
    }
    #pragma unroll
    for (int j = 0; j < 21; j++) {
        int yy = h + j - 10;
        if ((unsigned)yy < 256u) acc += wvc[j] * b2f(base[yy * 256 + w]);
    }
    o[(size_t)bc * HW + h * 256 + w] = f2bu(acc);
}

// ---------------------------------------------------------------------------
// K3: 1x1 conv (64x64) per pixel. which==0 -> writes Q-source in attn row
// layout [bh][w][h*8+c']; which==1 -> same layout (K) + transposed V layout
// [bh][h*8+c'][w].
__global__ __launch_bounds__(256) void k_pw(
        const unsigned short* __restrict__ in1, const unsigned short* __restrict__ in2,
        const float* __restrict__ wpw, const float* __restrict__ bpw,
        unsigned short* __restrict__ Eq, unsigned short* __restrict__ Fk,
        unsigned short* __restrict__ Fv) {
    __shared__ float sw[4096];
    __shared__ float sb[64];
    for (int i = threadIdx.x; i < 4096; i += 256) sw[i] = wpw[i];
    if (threadIdx.x < 64) sb[threadIdx.x] = bpw[threadIdx.x];
    __syncthreads();
    int which = blockIdx.y;
    const unsigned short* in = which ? in2 : in1;
    int row = blockIdx.x;              // b*256 + h
    int b = row >> 8, h = row & 255, w = threadIdx.x;
    size_t pix = (size_t)b * 64 * HW + h * 256 + w;
    float acc[64];
    #pragma unroll
    for (int o = 0; o < 64; o++) acc[o] = sb[o];
    for (int c = 0; c < 64; c++) {
        float xv = b2f(in[pix + (size_t)c * HW]);
        #pragma unroll
        for (int o = 0; o < 64; o++) acc[o] += sw[o * 64 + c] * xv;
    }
    unsigned short* dst = which ? Fk : Eq;
    #pragma unroll
    for (int hd = 0; hd < 8; hd++) {
        uint4 u;
        u.x = (unsigned)f2bu(acc[hd*8+0]) | ((unsigned)f2bu(acc[hd*8+1]) << 16);
        u.y = (unsigned)f2bu(acc[hd*8+2]) | ((unsigned)f2bu(acc[hd*8+3]) << 16);
        u.z = (unsigned)f2bu(acc[hd*8+4]) | ((unsigned)f2bu(acc[hd*8+5]) << 16);
        u.w = (unsigned)f2bu(acc[hd*8+6]) | ((unsigned)f2bu(acc[hd*8+7]) << 16);
        *(uint4*)(dst + ((size_t)(b*8+hd)*256 + w)*2048 + h*8) = u;
    }
    if (which) {
        #pragma unroll
        for (int o = 0; o < 64; o++) {
            Fv[((size_t)(b*8 + (o >> 3))*2048 + h*8 + (o & 7))*256 + w] = f2bu(acc[o]);
        }
    }
}

// ---------------------------------------------------------------------------
// K4: inverse L2 norms of Q rows and K rows (1 wave per 2048-elem row).
__global__ __launch_bounds__(256) void k_norm(
        const unsigned short* __restrict__ Eq, const unsigned short* __restrict__ Fk,
        float* __restrict__ invQ, float* __restrict__ invK) {
    int lane = threadIdx.x & 63, wid = threadIdx.x >> 6;
    int row = blockIdx.x * 4 + wid;    // 0..16383
    const unsigned short* src = (row < 8192) ? Eq : Fk;
    int r = row & 8191;
    const unsigned short* p = src + (size_t)r * 2048;
    float s = 0.f;
    #pragma unroll
    for (int it = 0; it < 4; it++) {
        uint4 u = *(const uint4*)(p + it * 512 + lane * 8);
        unsigned vals[4] = {u.x, u.y, u.z, u.w};
        #pragma unroll
        for (int e = 0; e < 4; e++) {
            float lo = b2f((unsigned short)(vals[e] & 0xffffu));
            float hi = b2f((unsigned short)(vals[e] >> 16));
            s += lo * lo + hi * hi;
        }
    }
    #pragma unroll
    for (int m = 1; m < 64; m <<= 1) s += __shfl_xor(s, m, 64);
    if (lane == 0) {
        float inv = 1.f / fmaxf(sqrtf(s), 1e-12f);
        (row < 8192 ? invQ : invK)[r] = inv;
    }
}

// ---------------------------------------------------------------------------
// K5: fused attention per (bh, 32-row tile). MFMA QK^T (scaled by invQ*invK)
// -> LDS softmax -> MFMA PV + Qn epilogue -> out4 in NCHW bf16.
// MFMA 16x16x32 layouts: A row=lane&15, k=(lane>>4)*8+j (contig 8);
// B col=lane&15, same k; C/D col=lane&15, row=(lane>>4)*4+reg.
__global__ __launch_bounds__(256) void k_attn(
        const unsigned short* __restrict__ Eq, const unsigned short* __restrict__ Fk,
        const unsigned short* __restrict__ Fv,
        const float* __restrict__ invQ, const float* __restrict__ invK,
        unsigned short* __restrict__ G) {
    __shared__ float Sbuf[32][257];
    __shared__ __align__(16) unsigned short Pbuf[32][264];
    __shared__ float sQ[32];
    __shared__ float sK[256];
    int bx = blockIdx.x;
    int bh = bx >> 3, itile = bx & 7, i0 = itile * 32;
    int b = bh >> 3, hd = bh & 7;
    const unsigned short* Q  = Eq + (size_t)bh * 256 * 2048;
    const unsigned short* Kp = Fk + (size_t)bh * 256 * 2048;
    const unsigned short* Vt = Fv + (size_t)bh * 2048 * 256;
    int tid = threadIdx.x, lane = tid & 63, wid = tid >> 6;
    if (tid < 32) sQ[tid] = invQ[bh * 256 + i0 + tid];
    sK[tid] = invK[bh * 256 + tid];
    __syncthreads();

    int rA = lane & 15, kf = (lane >> 4) * 8;

    // ---- QK^T ----
    f32x4 acc[2][4];
    #pragma unroll
    for (int ib = 0; ib < 2; ib++)
        #pragma unroll
        for (int jb = 0; jb < 4; jb++) acc[ib][jb] = (f32x4){0.f, 0.f, 0.f, 0.f};

    const unsigned short* q0  = Q  + (size_t)(i0 + rA) * 2048 + kf;
    const unsigned short* q1  = q0 + 16 * 2048;
    const unsigned short* kr0 = Kp + (size_t)(wid * 64 + rA) * 2048 + kf;
    for (int k0 = 0; k0 < 2048; k0 += 32) {
        bf16x8 a0 = *(const bf16x8*)(q0 + k0);
        bf16x8 a1 = *(const bf16x8*)(q1 + k0);
        #pragma unroll
        for (int jb = 0; jb < 4; jb++) {
            bf16x8 bb = *(const bf16x8*)(kr0 + (size_t)jb * 16 * 2048 + k0);
            acc[0][jb] = __builtin_amdgcn_mfma_f32_16x16x32_bf16(a0, bb, acc[0][jb], 0, 0, 0);
            acc[1][jb] = __builtin_amdgcn_mfma_f32_16x16x32_bf16(a1, bb, acc[1][jb], 0, 0, 0);
        }
    }
    #pragma unroll
    for (int ib = 0; ib < 2; ib++)
        #pragma unroll
        for (int jb = 0; jb < 4; jb++)
            #pragma unroll
            for (int r = 0; r < 4; r++) {
                int il = ib * 16 + (lane >> 4) * 4 + r;
                int jl = wid * 64 + jb * 16 + rA;
                Sbuf[il][jl] = acc[ib][jb][r] * sQ[il] * sK[jl];
            }
    __syncthreads();

    // ---- softmax over each of 32 rows (8 threads per row) ----
    {
        int r = tid >> 3, sub = tid & 7;
        float m = -1e30f;
        for (int j = sub * 32; j < sub * 32 + 32; j++) m = fmaxf(m, Sbuf[r][j]);
        #pragma unroll
        for (int msk = 1; msk < 8; msk <<= 1) m = fmaxf(m, __shfl_xor(m, msk, 8));
        float s = 0.f;
        for (int j = sub * 32; j < sub * 32 + 32; j++) {
            float e = __expf(Sbuf[r][j] - m);
            Sbuf[r][j] = e;
            s += e;
        }
        #pragma unroll
        for (int msk = 1; msk < 8; msk <<= 1) s += __shfl_xor(s, msk, 8);
        float inv = 1.f / s;
        for (int j = sub * 32; j < sub * 32 + 32; j++) Pbuf[r][j] = f2bu(Sbuf[r][j] * inv);
    }
    __syncthreads();

    // ---- PV + Qn, write NCHW ----
    bf16x8 pa[2][8];
    #pragma unroll
    for (int ib = 0; ib < 2; ib++)
        #pragma unroll
        for (int ks = 0; ks < 8; ks++)
            pa[ib][ks] = *(const bf16x8*)&Pbuf[ib * 16 + rA][ks * 32 + kf];

    int dbase = wid * 512;
    for (int dt = 0; dt < 32; dt++) {
        int d0 = dbase + dt * 16;
        f32x4 o0 = {0.f, 0.f, 0.f, 0.f}, o1 = {0.f, 0.f, 0.f, 0.f};
        const unsigned short* vb = Vt + (size_t)(d0 + rA) * 256 + kf;
        #pragma unroll
        for (int ks = 0; ks < 8; ks++) {
            bf16x8 bb = *(const bf16x8*)(vb + ks * 32);
            o0 = __builtin_amdgcn_mfma_f32_16x16x32_bf16(pa[0][ks], bb, o0, 0, 0, 0);
            o1 = __builtin_amdgcn_mfma_f32_16x16x32_bf16(pa[1][ks], bb, o1, 0, 0, 0);
        }
        int d = d0 + rA;
        int cpr = d & 7, hh = d >> 3;
        #pragma unroll
        for (int ib = 0; ib < 2; ib++) {
            f32x4 oa = ib ? o1 : o0;
            int ibase = i0 + ib * 16 + (lane >> 4) * 4;
            ushort4 pk;
            #pragma unroll
            for (int r = 0; r < 4; r++) {
                int il = ib * 16 + (lane >> 4) * 4 + r;
                float qv = b2f(Q[(size_t)(i0 + il) * 2048 + d]) * sQ[il];
                ((unsigned short*)&pk)[r] = f2bu(oa[r] + qv);
            }
            *(ushort4*)(G + (size_t)(b * 64 + hd * 8 + cpr) * HW + hh * 256 + ibase) = pk;
        }
    }
}

// ---------------------------------------------------------------------------
// K6: out = PW(out4) + LN(x1) + LN(x2)  (LN recomputed in fp32), fp32 out.
__global__ __launch_bounds__(256) void k_final(
        const unsigned short* __restrict__ G,
        const float* __restrict__ x1, const float* __restrict__ x2,
        const float* __restrict__ wpw, const float* __restrict__ bpw,
        const float* __restrict__ w1, const float* __restrict__ b1,
        const float* __restrict__ w2, const float* __restrict__ b2,
        float* __restrict__ out) {
    __shared__ float sw[4096];
    __shared__ float sb[64], s1w[64], s1b[64], s2w[64], s2b[64];
    for (int i = threadIdx.x; i < 4096; i += 256) sw[i] = wpw[i];
    if (threadIdx.x < 64) {
        sb[threadIdx.x]  = bpw[threadIdx.x];
        s1w[threadIdx.x] = w1[threadIdx.x];
        s1b[threadIdx.x] = b1[threadIdx.x];
        s2w[threadIdx.x] = w2[threadIdx.x];
        s2b[threadIdx.x] = b2[threadIdx.x];
    }
    __syncthreads();
    int p = blockIdx.x * 256 + threadIdx.x;
    int b = p >> 16, hw = p & (HW - 1);
    size_t base = (size_t)b * 64 * HW + hw;
    float acc[64];
    #pragma unroll
    for (int o = 0; o < 64; o++) acc[o] = sb[o];
    for (int c = 0; c < 64; c++) {
        float gv = b2f(G[base + (size_t)c * HW]);
        #pragma unroll
        for (int o = 0; o < 64; o++) acc[o] += sw[o * 64 + c] * gv;
    }
    float v[64];
    {
        float s = 0.f;
        #pragma unroll
        for (int c = 0; c < 64; c++) { v[c] = x1[base + (size_t)c * HW]; s += v[c]; }
        float mu = s * 0.015625f, s2 = 0.f;
        #pragma unroll
        for (int c = 0; c < 64; c++) { float d = v[c] - mu; s2 += d * d; }
        float rstd = rsqrtf(s2 * 0.015625f + 1e-5f);
        #pragma unroll
        for (int c = 0; c < 64; c++) acc[c] += (v[c] - mu) * rstd * s1w[c] + s1b[c];
    }
    {
        float s = 0.f;
        #pragma unroll
        for (int c = 0; c < 64; c++) { v[c] = x2[base + (size_t)c * HW]; s += v[c]; }
        float mu = s * 0.015625f, s2 = 0.f;
        #pragma unroll
        for (int c = 0; c < 64; c++) { float d = v[c] - mu; s2 += d * d; }
        float rstd = rsqrtf(s2 * 0.015625f + 1e-5f);
        #pragma unroll
        for (int c = 0; c < 64; c++) acc[c] += (v[c] - mu) * rstd * s2w[c] + s2b[c];
    }
    #pragma unroll
    for (int c = 0; c < 64; c++) out[base + (size_t)c * HW] = acc[c];
}

// ---------------------------------------------------------------------------
extern "C" void kernel_launch(void* const* d_in, const int* in_sizes, int n_in,
                              void* d_out, int out_size, void* d_ws, size_t ws_size,
                              hipStream_t stream) {
    const float* x1   = (const float*)d_in[0];
    const float* x2   = (const float*)d_in[1];
    const float* ln1w = (const float*)d_in[2];
    const float* ln1b = (const float*)d_in[3];
    const float* ln2w = (const float*)d_in[4];
    const float* ln2b = (const float*)d_in[5];
    const float* bdw  = (const float*)d_in[6];
    const float* wpw  = (const float*)d_in[7];
    const float* bpw  = (const float*)d_in[8];
    const float* kk[12];
    for (int i = 0; i < 12; i++) kk[i] = (const float*)d_in[9 + i];

    char* ws = (char*)d_ws;
    float* wcomb = (float*)ws;              // 5376 floats
    float* bias  = (float*)(ws + 21504);    // 128 floats
    float* invQ  = (float*)(ws + 32768);    // 8192 floats
    float* invK  = (float*)(ws + 65536);    // 8192 floats
    const size_t SMALL = 131072;
    const size_t SZ = 33554432;             // 16.7M bf16 elements

    // Region plan (reuse): R0 = x1n -> Qsrc, R1 = x2n -> Ksrc,
    // R2 = dw1 -> out4, R3 = dw2, R4 = Vt. If ws is too small, borrow d_out
    // (64 MiB = 2 regions) for R3/R4 — both are dead before k_final writes out.
    unsigned short* R0 = (unsigned short*)(ws + SMALL);
    unsigned short* R1 = (unsigned short*)(ws + SMALL + SZ);
    unsigned short* R2 = (unsigned short*)(ws + SMALL + 2 * SZ);
    unsigned short *R3, *R4;
    if (ws_size >= SMALL + 5 * SZ) {
        R3 = (unsigned short*)(ws + SMALL + 3 * SZ);
        R4 = (unsigned short*)(ws + SMALL + 4 * SZ);
    } else {
        R3 = (unsigned short*)d_out;
        R4 = (unsigned short*)((char*)d_out + SZ);
    }

    k_prep<<<1, 64, 0, stream>>>(kk[0], kk[1], kk[2], kk[3], kk[4], kk[5],
                                 kk[6], kk[7], kk[8], kk[9], kk[10], kk[11],
                                 bdw, wcomb, bias);
    k_ln<<<dim3(1024, 2), 256, 0, stream>>>(x1, x2, ln1w, ln1b, ln2w, ln2b, R0, R1);
    k_dw<<<dim3(65536, 2), 256, 0, stream>>>(R0, R1, wcomb, bias, R2, R3);
    k_pw<<<dim3(1024, 2), 256, 0, stream>>>(R2, R3, wpw, bpw, R0, R1, R4);
    k_norm<<<4096, 256, 0, stream>>>(R0, R1, invQ, invK);
    k_attn<<<256, 256, 0, stream>>>(R0, R1, R4, invQ, invK, R2);
    k_final<<<1024, 256, 0, stream>>>(R2, x1, x2, wpw, bpw,
                                      ln1w, ln1b, ln2w, ln2b, (float*)d_out);
}

// Round 2
// 530.053 us; speedup vs baseline: 2.2264x; 2.2264x over previous
//
#include <hip/hip_runtime.h>

#define HW 65536  // 256*256

typedef __bf16 bf16x8 __attribute__((ext_vector_type(8)));
typedef float f32x4 __attribute__((ext_vector_type(4)));

__device__ __forceinline__ float b2f(unsigned short u) {
    return __uint_as_float(((unsigned)u) << 16);
}
__device__ __forceinline__ unsigned short f2bu(float f) {
    unsigned u = __float_as_uint(f);
    return (unsigned short)((u + 0x7FFFu + ((u >> 16) & 1u)) >> 16);
}
// unpack a u32 holding 2 bf16 -> 2 floats (1 VALU op each)
__device__ __forceinline__ void up2(unsigned u, float& lo, float& hi) {
    lo = __uint_as_float(u << 16);
    hi = __uint_as_float(u & 0xFFFF0000u);
}

// ---------------------------------------------------------------------------
// K0: fold 6 depthwise kernels -> combined 21-tap h + 21-tap v per tensor,
// and sum the 6 biases per tensor. wcomb layout: wh1|wv1|wh2|wv2, each 64*21.
__global__ void k_prep(const float* k11, const float* k12, const float* k13,
                       const float* k14, const float* k15, const float* k16,
                       const float* k21, const float* k22, const float* k23,
                       const float* k24, const float* k25, const float* k26,
                       const float* bdw, float* wcomb, float* bias) {
    int c = threadIdx.x;
    if (c >= 64) return;
    float* wh1 = wcomb;
    float* wv1 = wcomb + 1344;
    float* wh2 = wcomb + 2688;
    float* wv2 = wcomb + 4032;
    for (int j = 0; j < 21; j++) {
        wh1[c*21+j] = k13[c*21+j];
        wv1[c*21+j] = k16[c*21+j];
        wh2[c*21+j] = k23[c*21+j];
        wv2[c*21+j] = k26[c*21+j];
    }
    for (int j = 0; j < 11; j++) {
        wh1[c*21+j+5] += k12[c*11+j];
        wv1[c*21+j+5] += k15[c*11+j];
        wh2[c*21+j+5] += k22[c*11+j];
        wv2[c*21+j+5] += k25[c*11+j];
    }
    for (int j = 0; j < 7; j++) {
        wh1[c*21+j+7] += k11[c*7+j];
        wv1[c*21+j+7] += k14[c*7+j];
        wh2[c*21+j+7] += k21[c*7+j];
        wv2[c*21+j+7] += k24[c*7+j];
    }
    float s1 = 0.f, s2 = 0.f;
    for (int i = 0; i < 6; i++) { s1 += bdw[i*64+c]; s2 += bdw[(6+i)*64+c]; }
    bias[c] = s1; bias[64+c] = s2;
}

// ---------------------------------------------------------------------------
// K1: per-pixel LayerNorm over 64 channels, fp32 in -> bf16 out (NCHW).
__global__ __launch_bounds__(256) void k_ln(
        const float* __restrict__ x1, const float* __restrict__ x2,
        const float* __restrict__ w1, const float* __restrict__ b1,
        const float* __restrict__ w2, const float* __restrict__ b2,
        unsigned short* __restrict__ o1, unsigned short* __restrict__ o2) {
    int which = blockIdx.y;
    const float* x  = which ? x2 : x1;
    const float* lw = which ? w2 : w1;
    const float* lb = which ? b2 : b1;
    unsigned short* o = which ? o2 : o1;
    int p = blockIdx.x * 256 + threadIdx.x;   // 0..262143
    int b = p >> 16, hw = p & (HW - 1);
    size_t base = (size_t)b * 64 * HW + hw;
    float v[64];
    float s = 0.f;
    #pragma unroll
    for (int c = 0; c < 64; c++) { v[c] = x[base + (size_t)c * HW]; s += v[c]; }
    float mu = s * 0.015625f;
    float s2 = 0.f;
    #pragma unroll
    for (int c = 0; c < 64; c++) { float d = v[c] - mu; s2 += d * d; }
    float rstd = rsqrtf(s2 * 0.015625f + 1e-5f);
    #pragma unroll
    for (int c = 0; c < 64; c++)
        o[base + (size_t)c * HW] = f2bu((v[c] - mu) * rstd * lw[c] + lb[c]);
}

// ---------------------------------------------------------------------------
// K2: combined depthwise conv (21-tap h + 21-tap v + bias), LDS-tiled.
// Block = one (bc, 32-row tile). LDS tile 52 rows x 288 cols bf16 (16-col
// zero pads both sides, 10-row halo top/bottom). Thread (seg,rgrp) computes
// an 8-wide x 4-row patch: vertical via 24 rolling ds_read_b128, horizontal
// via 8 ds_read_b64 per row. All FMA unrolled in registers.
__global__ __launch_bounds__(256) void k_dw(
        const unsigned short* __restrict__ in1, const unsigned short* __restrict__ in2,
        const float* __restrict__ wcomb, const float* __restrict__ bias,
        unsigned short* __restrict__ o1, unsigned short* __restrict__ o2) {
    __shared__ __align__(16) unsigned short tile[52][288];
    int which = blockIdx.y;
    const unsigned short* in = which ? in2 : in1;
    unsigned short* o = which ? o2 : o1;
    int bx = blockIdx.x;               // bc*8 + tileid
    int bc = bx >> 3, tileid = bx & 7;
    int c = bc & 63;
    int h0 = tileid * 32;
    const float* whp = wcomb + which * 2688 + c * 21;
    const float* wvp = whp + 1344;
    float wh[21], wv[21];
    #pragma unroll
    for (int j = 0; j < 21; j++) { wh[j] = whp[j]; wv[j] = wvp[j]; }
    float bs = bias[which * 64 + c];
    const unsigned short* src = in + (size_t)bc * HW;
    int tid = threadIdx.x;

    // stage 52 rows x 36 chunks (8 bf16 each); chunks 0,1,34,35 are zero pads
    for (int idx = tid; idx < 52 * 36; idx += 256) {
        int row = idx / 36, chunk = idx - row * 36;
        int grow = h0 - 10 + row;
        uint4 val = make_uint4(0u, 0u, 0u, 0u);
        if ((unsigned)grow < 256u && chunk >= 2 && chunk <= 33)
            val = *(const uint4*)(src + grow * 256 + (chunk - 2) * 8);
        *(uint4*)&tile[row][chunk * 8] = val;
    }
    __syncthreads();

    int seg = tid & 31, rgrp = tid >> 5;
    int w0 = seg * 8;                  // global w base of this thread's patch
    int r0 = rgrp * 4;                 // local output row base (global h = h0+r0+k)

    float acc[4][8];
    #pragma unroll
    for (int k = 0; k < 4; k++)
        #pragma unroll
        for (int i = 0; i < 8; i++) acc[k][i] = bs;

    // ---- vertical: tile rows r0 .. r0+23 each feed up to 4 output rows ----
    #pragma unroll
    for (int rr = 0; rr < 24; rr++) {
        uint4 u = *(const uint4*)&tile[r0 + rr][16 + w0];
        float v[8];
        up2(u.x, v[0], v[1]); up2(u.y, v[2], v[3]);
        up2(u.z, v[4], v[5]); up2(u.w, v[6], v[7]);
        #pragma unroll
        for (int k = 0; k < 4; k++) {
            const int j = rr - k;
            if (j >= 0 && j < 21) {
                float wt = wv[j];
                #pragma unroll
                for (int i = 0; i < 8; i++) acc[k][i] += wt * v[i];
            }
        }
    }

    // ---- horizontal: per output row, 32-val window [w0-12, w0+20) ----
    #pragma unroll
    for (int k = 0; k < 4; k++) {
        const unsigned short* rowp = &tile[r0 + k + 10][w0 + 4]; // col w0+4 = global w0-12
        float hv[32];
        #pragma unroll
        for (int q = 0; q < 8; q++) {
            uint2 u = *(const uint2*)(rowp + q * 4);
            up2(u.x, hv[q*4+0], hv[q*4+1]);
            up2(u.y, hv[q*4+2], hv[q*4+3]);
        }
        // out px i needs x[w0+i+j-10] = hv[i+j+2]
        #pragma unroll
        for (int j = 0; j < 21; j++) {
            float wt = wh[j];
            #pragma unroll
            for (int i = 0; i < 8; i++) acc[k][i] += wt * hv[i + j + 2];
        }
    }

    // ---- write 4 rows x 8 px ----
    size_t obase = (size_t)bc * HW;
    #pragma unroll
    for (int k = 0; k < 4; k++) {
        uint4 u;
        u.x = (unsigned)f2bu(acc[k][0]) | ((unsigned)f2bu(acc[k][1]) << 16);
        u.y = (unsigned)f2bu(acc[k][2]) | ((unsigned)f2bu(acc[k][3]) << 16);
        u.z = (unsigned)f2bu(acc[k][4]) | ((unsigned)f2bu(acc[k][5]) << 16);
        u.w = (unsigned)f2bu(acc[k][6]) | ((unsigned)f2bu(acc[k][7]) << 16);
        *(uint4*)(o + obase + (size_t)(h0 + r0 + k) * 256 + w0) = u;
    }
}

// ---------------------------------------------------------------------------
// K3: 1x1 conv (64x64) per pixel. which==0 -> writes Q-source in attn row
// layout [bh][w][h*8+c']; which==1 -> same layout (K) + transposed V layout
// [bh][h*8+c'][w].
__global__ __launch_bounds__(256) void k_pw(
        const unsigned short* __restrict__ in1, const unsigned short* __restrict__ in2,
        const float* __restrict__ wpw, const float* __restrict__ bpw,
        unsigned short* __restrict__ Eq, unsigned short* __restrict__ Fk,
        unsigned short* __restrict__ Fv) {
    __shared__ float sw[4096];
    __shared__ float sb[64];
    for (int i = threadIdx.x; i < 4096; i += 256) sw[i] = wpw[i];
    if (threadIdx.x < 64) sb[threadIdx.x] = bpw[threadIdx.x];
    __syncthreads();
    int which = blockIdx.y;
    const unsigned short* in = which ? in2 : in1;
    int row = blockIdx.x;              // b*256 + h
    int b = row >> 8, h = row & 255, w = threadIdx.x;
    size_t pix = (size_t)b * 64 * HW + h * 256 + w;
    float acc[64];
    #pragma unroll
    for (int o = 0; o < 64; o++) acc[o] = sb[o];
    for (int c = 0; c < 64; c++) {
        float xv = b2f(in[pix + (size_t)c * HW]);
        #pragma unroll
        for (int o = 0; o < 64; o++) acc[o] += sw[o * 64 + c] * xv;
    }
    unsigned short* dst = which ? Fk : Eq;
    #pragma unroll
    for (int hd = 0; hd < 8; hd++) {
        uint4 u;
        u.x = (unsigned)f2bu(acc[hd*8+0]) | ((unsigned)f2bu(acc[hd*8+1]) << 16);
        u.y = (unsigned)f2bu(acc[hd*8+2]) | ((unsigned)f2bu(acc[hd*8+3]) << 16);
        u.z = (unsigned)f2bu(acc[hd*8+4]) | ((unsigned)f2bu(acc[hd*8+5]) << 16);
        u.w = (unsigned)f2bu(acc[hd*8+6]) | ((unsigned)f2bu(acc[hd*8+7]) << 16);
        *(uint4*)(dst + ((size_t)(b*8+hd)*256 + w)*2048 + h*8) = u;
    }
    if (which) {
        #pragma unroll
        for (int o = 0; o < 64; o++) {
            Fv[((size_t)(b*8 + (o >> 3))*2048 + h*8 + (o & 7))*256 + w] = f2bu(acc[o]);
        }
    }
}

// ---------------------------------------------------------------------------
// K4: inverse L2 norms of Q rows and K rows (1 wave per 2048-elem row).
__global__ __launch_bounds__(256) void k_norm(
        const unsigned short* __restrict__ Eq, const unsigned short* __restrict__ Fk,
        float* __restrict__ invQ, float* __restrict__ invK) {
    int lane = threadIdx.x & 63, wid = threadIdx.x >> 6;
    int row = blockIdx.x * 4 + wid;    // 0..16383
    const unsigned short* src = (row < 8192) ? Eq : Fk;
    int r = row & 8191;
    const unsigned short* p = src + (size_t)r * 2048;
    float s = 0.f;
    #pragma unroll
    for (int it = 0; it < 4; it++) {
        uint4 u = *(const uint4*)(p + it * 512 + lane * 8);
        unsigned vals[4] = {u.x, u.y, u.z, u.w};
        #pragma unroll
        for (int e = 0; e < 4; e++) {
            float lo = b2f((unsigned short)(vals[e] & 0xffffu));
            float hi = b2f((unsigned short)(vals[e] >> 16));
            s += lo * lo + hi * hi;
        }
    }
    #pragma unroll
    for (int m = 1; m < 64; m <<= 1) s += __shfl_xor(s, m, 64);
    if (lane == 0) {
        float inv = 1.f / fmaxf(sqrtf(s), 1e-12f);
        (row < 8192 ? invQ : invK)[r] = inv;
    }
}

// ---------------------------------------------------------------------------
// K5: fused attention per (bh, 32-row tile). MFMA QK^T (scaled by invQ*invK)
// -> LDS softmax -> MFMA PV + Qn epilogue -> out4 in NCHW bf16.
// MFMA 16x16x32 layouts: A row=lane&15, k=(lane>>4)*8+j (contig 8);
// B col=lane&15, same k; C/D col=lane&15, row=(lane>>4)*4+reg.
__global__ __launch_bounds__(256) void k_attn(
        const unsigned short* __restrict__ Eq, const unsigned short* __restrict__ Fk,
        const unsigned short* __restrict__ Fv,
        const float* __restrict__ invQ, const float* __restrict__ invK,
        unsigned short* __restrict__ G) {
    __shared__ float Sbuf[32][257];
    __shared__ __align__(16) unsigned short Pbuf[32][264];
    __shared__ float sQ[32];
    __shared__ float sK[256];
    int bx = blockIdx.x;
    int bh = bx >> 3, itile = bx & 7, i0 = itile * 32;
    int b = bh >> 3, hd = bh & 7;
    const unsigned short* Q  = Eq + (size_t)bh * 256 * 2048;
    const unsigned short* Kp = Fk + (size_t)bh * 256 * 2048;
    const unsigned short* Vt = Fv + (size_t)bh * 2048 * 256;
    int tid = threadIdx.x, lane = tid & 63, wid = tid >> 6;
    if (tid < 32) sQ[tid] = invQ[bh * 256 + i0 + tid];
    sK[tid] = invK[bh * 256 + tid];
    __syncthreads();

    int rA = lane & 15, kf = (lane >> 4) * 8;

    // ---- QK^T ----
    f32x4 acc[2][4];
    #pragma unroll
    for (int ib = 0; ib < 2; ib++)
        #pragma unroll
        for (int jb = 0; jb < 4; jb++) acc[ib][jb] = (f32x4){0.f, 0.f, 0.f, 0.f};

    const unsigned short* q0  = Q  + (size_t)(i0 + rA) * 2048 + kf;
    const unsigned short* q1  = q0 + 16 * 2048;
    const unsigned short* kr0 = Kp + (size_t)(wid * 64 + rA) * 2048 + kf;
    for (int k0 = 0; k0 < 2048; k0 += 32) {
        bf16x8 a0 = *(const bf16x8*)(q0 + k0);
        bf16x8 a1 = *(const bf16x8*)(q1 + k0);
        #pragma unroll
        for (int jb = 0; jb < 4; jb++) {
            bf16x8 bb = *(const bf16x8*)(kr0 + (size_t)jb * 16 * 2048 + k0);
            acc[0][jb] = __builtin_amdgcn_mfma_f32_16x16x32_bf16(a0, bb, acc[0][jb], 0, 0, 0);
            acc[1][jb] = __builtin_amdgcn_mfma_f32_16x16x32_bf16(a1, bb, acc[1][jb], 0, 0, 0);
        }
    }
    #pragma unroll
    for (int ib = 0; ib < 2; ib++)
        #pragma unroll
        for (int jb = 0; jb < 4; jb++)
            #pragma unroll
            for (int r = 0; r < 4; r++) {
                int il = ib * 16 + (lane >> 4) * 4 + r;
                int jl = wid * 64 + jb * 16 + rA;
                Sbuf[il][jl] = acc[ib][jb][r] * sQ[il] * sK[jl];
            }
    __syncthreads();

    // ---- softmax over each of 32 rows (8 threads per row) ----
    {
        int r = tid >> 3, sub = tid & 7;
        float m = -1e30f;
        for (int j = sub * 32; j < sub * 32 + 32; j++) m = fmaxf(m, Sbuf[r][j]);
        #pragma unroll
        for (int msk = 1; msk < 8; msk <<= 1) m = fmaxf(m, __shfl_xor(m, msk, 8));
        float s = 0.f;
        for (int j = sub * 32; j < sub * 32 + 32; j++) {
            float e = __expf(Sbuf[r][j] - m);
            Sbuf[r][j] = e;
            s += e;
        }
        #pragma unroll
        for (int msk = 1; msk < 8; msk <<= 1) s += __shfl_xor(s, msk, 8);
        float inv = 1.f / s;
        for (int j = sub * 32; j < sub * 32 + 32; j++) Pbuf[r][j] = f2bu(Sbuf[r][j] * inv);
    }
    __syncthreads();

    // ---- PV + Qn, write NCHW ----
    bf16x8 pa[2][8];
    #pragma unroll
    for (int ib = 0; ib < 2; ib++)
        #pragma unroll
        for (int ks = 0; ks < 8; ks++)
            pa[ib][ks] = *(const bf16x8*)&Pbuf[ib * 16 + rA][ks * 32 + kf];

    int dbase = wid * 512;
    for (int dt = 0; dt < 32; dt++) {
        int d0 = dbase + dt * 16;
        f32x4 o0 = {0.f, 0.f, 0.f, 0.f}, o1 = {0.f, 0.f, 0.f, 0.f};
        const unsigned short* vb = Vt + (size_t)(d0 + rA) * 256 + kf;
        #pragma unroll
        for (int ks = 0; ks < 8; ks++) {
            bf16x8 bb = *(const bf16x8*)(vb + ks * 32);
            o0 = __builtin_amdgcn_mfma_f32_16x16x32_bf16(pa[0][ks], bb, o0, 0, 0, 0);
            o1 = __builtin_amdgcn_mfma_f32_16x16x32_bf16(pa[1][ks], bb, o1, 0, 0, 0);
        }
        int d = d0 + rA;
        int cpr = d & 7, hh = d >> 3;
        #pragma unroll
        for (int ib = 0; ib < 2; ib++) {
            f32x4 oa = ib ? o1 : o0;
            int ibase = i0 + ib * 16 + (lane >> 4) * 4;
            ushort4 pk;
            #pragma unroll
            for (int r = 0; r < 4; r++) {
                int il = ib * 16 + (lane >> 4) * 4 + r;
                float qv = b2f(Q[(size_t)(i0 + il) * 2048 + d]) * sQ[il];
                ((unsigned short*)&pk)[r] = f2bu(oa[r] + qv);
            }
            *(ushort4*)(G + (size_t)(b * 64 + hd * 8 + cpr) * HW + hh * 256 + ibase) = pk;
        }
    }
}

// ---------------------------------------------------------------------------
// K6: out = PW(out4) + LN(x1) + LN(x2)  (LN recomputed in fp32), fp32 out.
__global__ __launch_bounds__(256) void k_final(
        const unsigned short* __restrict__ G,
        const float* __restrict__ x1, const float* __restrict__ x2,
        const float* __restrict__ wpw, const float* __restrict__ bpw,
        const float* __restrict__ w1, const float* __restrict__ b1,
        const float* __restrict__ w2, const float* __restrict__ b2,
        float* __restrict__ out) {
    __shared__ float sw[4096];
    __shared__ float sb[64], s1w[64], s1b[64], s2w[64], s2b[64];
    for (int i = threadIdx.x; i < 4096; i += 256) sw[i] = wpw[i];
    if (threadIdx.x < 64) {
        sb[threadIdx.x]  = bpw[threadIdx.x];
        s1w[threadIdx.x] = w1[threadIdx.x];
        s1b[threadIdx.x] = b1[threadIdx.x];
        s2w[threadIdx.x] = w2[threadIdx.x];
        s2b[threadIdx.x] = b2[threadIdx.x];
    }
    __syncthreads();
    int p = blockIdx.x * 256 + threadIdx.x;
    int b = p >> 16, hw = p & (HW - 1);
    size_t base = (size_t)b * 64 * HW + hw;
    float acc[64];
    #pragma unroll
    for (int o = 0; o < 64; o++) acc[o] = sb[o];
    for (int c = 0; c < 64; c++) {
        float gv = b2f(G[base + (size_t)c * HW]);
        #pragma unroll
        for (int o = 0; o < 64; o++) acc[o] += sw[o * 64 + c] * gv;
    }
    float v[64];
    {
        float s = 0.f;
        #pragma unroll
        for (int c = 0; c < 64; c++) { v[c] = x1[base + (size_t)c * HW]; s += v[c]; }
        float mu = s * 0.015625f, s2 = 0.f;
        #pragma unroll
        for (int c = 0; c < 64; c++) { float d = v[c] - mu; s2 += d * d; }
        float rstd = rsqrtf(s2 * 0.015625f + 1e-5f);
        #pragma unroll
        for (int c = 0; c < 64; c++) acc[c] += (v[c] - mu) * rstd * s1w[c] + s1b[c];
    }
    {
        float s = 0.f;
        #pragma unroll
        for (int c = 0; c < 64; c++) { v[c] = x2[base + (size_t)c * HW]; s += v[c]; }
        float mu = s * 0.015625f, s2 = 0.f;
        #pragma unroll
        for (int c = 0; c < 64; c++) { float d = v[c] - mu; s2 += d * d; }
        float rstd = rsqrtf(s2 * 0.015625f + 1e-5f);
        #pragma unroll
        for (int c = 0; c < 64; c++) acc[c] += (v[c] - mu) * rstd * s2w[c] + s2b[c];
    }
    #pragma unroll
    for (int c = 0; c < 64; c++) out[base + (size_t)c * HW] = acc[c];
}

// ---------------------------------------------------------------------------
extern "C" void kernel_launch(void* const* d_in, const int* in_sizes, int n_in,
                              void* d_out, int out_size, void* d_ws, size_t ws_size,
                              hipStream_t stream) {
    const float* x1   = (const float*)d_in[0];
    const float* x2   = (const float*)d_in[1];
    const float* ln1w = (const float*)d_in[2];
    const float* ln1b = (const float*)d_in[3];
    const float* ln2w = (const float*)d_in[4];
    const float* ln2b = (const float*)d_in[5];
    const float* bdw  = (const float*)d_in[6];
    const float* wpw  = (const float*)d_in[7];
    const float* bpw  = (const float*)d_in[8];
    const float* kk[12];
    for (int i = 0; i < 12; i++) kk[i] = (const float*)d_in[9 + i];

    char* ws = (char*)d_ws;
    float* wcomb = (float*)ws;              // 5376 floats
    float* bias  = (float*)(ws + 21504);    // 128 floats
    float* invQ  = (float*)(ws + 32768);    // 8192 floats
    float* invK  = (float*)(ws + 65536);    // 8192 floats
    const size_t SMALL = 131072;
    const size_t SZ = 33554432;             // 16.7M bf16 elements

    // Region plan (reuse): R0 = x1n -> Qsrc, R1 = x2n -> Ksrc,
    // R2 = dw1 -> out4, R3 = dw2, R4 = Vt. If ws is too small, borrow d_out
    // (64 MiB = 2 regions) for R3/R4 — both are dead before k_final writes out.
    unsigned short* R0 = (unsigned short*)(ws + SMALL);
    unsigned short* R1 = (unsigned short*)(ws + SMALL + SZ);
    unsigned short* R2 = (unsigned short*)(ws + SMALL + 2 * SZ);
    unsigned short *R3, *R4;
    if (ws_size >= SMALL + 5 * SZ) {
        R3 = (unsigned short*)(ws + SMALL + 3 * SZ);
        R4 = (unsigned short*)(ws + SMALL + 4 * SZ);
    } else {
        R3 = (unsigned short*)d_out;
        R4 = (unsigned short*)((char*)d_out + SZ);
    }

    k_prep<<<1, 64, 0, stream>>>(kk[0], kk[1], kk[2], kk[3], kk[4], kk[5],
                                 kk[6], kk[7], kk[8], kk[9], kk[10], kk[11],
                                 bdw, wcomb, bias);
    k_ln<<<dim3(1024, 2), 256, 0, stream>>>(x1, x2, ln1w, ln1b, ln2w, ln2b, R0, R1);
    k_dw<<<dim3(2048, 2), 256, 0, stream>>>(R0, R1, wcomb, bias, R2, R3);
    k_pw<<<dim3(1024, 2), 256, 0, stream>>>(R2, R3, wpw, bpw, R0, R1, R4);
    k_norm<<<4096, 256, 0, stream>>>(R0, R1, invQ, invK);
    k_attn<<<256, 256, 0, stream>>>(R0, R1, R4, invQ, invK, R2);
    k_final<<<1024, 256, 0, stream>>>(R2, x1, x2, wpw, bpw,
                                      ln1w, ln1b, ln2w, ln2b, (float*)d_out);
}

// Round 3
// 355.317 us; speedup vs baseline: 3.3213x; 1.4918x over previous
//
#include <hip/hip_runtime.h>

#define HW 65536  // 256*256

typedef __bf16 bf16x8 __attribute__((ext_vector_type(8)));
typedef float f32x4 __attribute__((ext_vector_type(4)));

__device__ __forceinline__ float b2f(unsigned short u) {
    return __uint_as_float(((unsigned)u) << 16);
}
__device__ __forceinline__ unsigned short f2bu(float f) {
    unsigned u = __float_as_uint(f);
    return (unsigned short)((u + 0x7FFFu + ((u >> 16) & 1u)) >> 16);
}
// unpack a u32 holding 2 bf16 -> 2 floats (1 VALU op each)
__device__ __forceinline__ void up2(unsigned u, float& lo, float& hi) {
    lo = __uint_as_float(u << 16);
    hi = __uint_as_float(u & 0xFFFF0000u);
}

// ---------------------------------------------------------------------------
// K0: fold 6 depthwise kernels -> combined 21-tap h + 21-tap v per tensor,
// and sum the 6 biases per tensor. wcomb layout: wh1|wv1|wh2|wv2, each 64*21.
__global__ void k_prep(const float* k11, const float* k12, const float* k13,
                       const float* k14, const float* k15, const float* k16,
                       const float* k21, const float* k22, const float* k23,
                       const float* k24, const float* k25, const float* k26,
                       const float* bdw, float* wcomb, float* bias) {
    int c = threadIdx.x;
    if (c >= 64) return;
    float* wh1 = wcomb;
    float* wv1 = wcomb + 1344;
    float* wh2 = wcomb + 2688;
    float* wv2 = wcomb + 4032;
    for (int j = 0; j < 21; j++) {
        wh1[c*21+j] = k13[c*21+j];
        wv1[c*21+j] = k16[c*21+j];
        wh2[c*21+j] = k23[c*21+j];
        wv2[c*21+j] = k26[c*21+j];
    }
    for (int j = 0; j < 11; j++) {
        wh1[c*21+j+5] += k12[c*11+j];
        wv1[c*21+j+5] += k15[c*11+j];
        wh2[c*21+j+5] += k22[c*11+j];
        wv2[c*21+j+5] += k25[c*11+j];
    }
    for (int j = 0; j < 7; j++) {
        wh1[c*21+j+7] += k11[c*7+j];
        wv1[c*21+j+7] += k14[c*7+j];
        wh2[c*21+j+7] += k21[c*7+j];
        wv2[c*21+j+7] += k24[c*7+j];
    }
    float s1 = 0.f, s2 = 0.f;
    for (int i = 0; i < 6; i++) { s1 += bdw[i*64+c]; s2 += bdw[(6+i)*64+c]; }
    bias[c] = s1; bias[64+c] = s2;
}

// ---------------------------------------------------------------------------
// K1: per-pixel LayerNorm over 64 channels, fp32 in -> bf16 out (NCHW).
__global__ __launch_bounds__(256) void k_ln(
        const float* __restrict__ x1, const float* __restrict__ x2,
        const float* __restrict__ w1, const float* __restrict__ b1,
        const float* __restrict__ w2, const float* __restrict__ b2,
        unsigned short* __restrict__ o1, unsigned short* __restrict__ o2) {
    int which = blockIdx.y;
    const float* x  = which ? x2 : x1;
    const float* lw = which ? w2 : w1;
    const float* lb = which ? b2 : b1;
    unsigned short* o = which ? o2 : o1;
    int p = blockIdx.x * 256 + threadIdx.x;   // 0..262143
    int b = p >> 16, hw = p & (HW - 1);
    size_t base = (size_t)b * 64 * HW + hw;
    float v[64];
    float s = 0.f;
    #pragma unroll
    for (int c = 0; c < 64; c++) { v[c] = x[base + (size_t)c * HW]; s += v[c]; }
    float mu = s * 0.015625f;
    float s2 = 0.f;
    #pragma unroll
    for (int c = 0; c < 64; c++) { float d = v[c] - mu; s2 += d * d; }
    float rstd = rsqrtf(s2 * 0.015625f + 1e-5f);
    #pragma unroll
    for (int c = 0; c < 64; c++)
        o[base + (size_t)c * HW] = f2bu((v[c] - mu) * rstd * lw[c] + lb[c]);
}

// ---------------------------------------------------------------------------
// K2: combined depthwise conv (21-tap h + 21-tap v + bias), LDS-tiled.
__global__ __launch_bounds__(256) void k_dw(
        const unsigned short* __restrict__ in1, const unsigned short* __restrict__ in2,
        const float* __restrict__ wcomb, const float* __restrict__ bias,
        unsigned short* __restrict__ o1, unsigned short* __restrict__ o2) {
    __shared__ __align__(16) unsigned short tile[52][288];
    int which = blockIdx.y;
    const unsigned short* in = which ? in2 : in1;
    unsigned short* o = which ? o2 : o1;
    int bx = blockIdx.x;               // bc*8 + tileid
    int bc = bx >> 3, tileid = bx & 7;
    int c = bc & 63;
    int h0 = tileid * 32;
    const float* whp = wcomb + which * 2688 + c * 21;
    const float* wvp = whp + 1344;
    float wh[21], wv[21];
    #pragma unroll
    for (int j = 0; j < 21; j++) { wh[j] = whp[j]; wv[j] = wvp[j]; }
    float bs = bias[which * 64 + c];
    const unsigned short* src = in + (size_t)bc * HW;
    int tid = threadIdx.x;

    // stage 52 rows x 36 chunks (8 bf16 each); chunks 0,1,34,35 are zero pads
    for (int idx = tid; idx < 52 * 36; idx += 256) {
        int row = idx / 36, chunk = idx - row * 36;
        int grow = h0 - 10 + row;
        uint4 val = make_uint4(0u, 0u, 0u, 0u);
        if ((unsigned)grow < 256u && chunk >= 2 && chunk <= 33)
            val = *(const uint4*)(src + grow * 256 + (chunk - 2) * 8);
        *(uint4*)&tile[row][chunk * 8] = val;
    }
    __syncthreads();

    int seg = tid & 31, rgrp = tid >> 5;
    int w0 = seg * 8;
    int r0 = rgrp * 4;

    float acc[4][8];
    #pragma unroll
    for (int k = 0; k < 4; k++)
        #pragma unroll
        for (int i = 0; i < 8; i++) acc[k][i] = bs;

    #pragma unroll
    for (int rr = 0; rr < 24; rr++) {
        uint4 u = *(const uint4*)&tile[r0 + rr][16 + w0];
        float v[8];
        up2(u.x, v[0], v[1]); up2(u.y, v[2], v[3]);
        up2(u.z, v[4], v[5]); up2(u.w, v[6], v[7]);
        #pragma unroll
        for (int k = 0; k < 4; k++) {
            const int j = rr - k;
            if (j >= 0 && j < 21) {
                float wt = wv[j];
                #pragma unroll
                for (int i = 0; i < 8; i++) acc[k][i] += wt * v[i];
            }
        }
    }

    #pragma unroll
    for (int k = 0; k < 4; k++) {
        const unsigned short* rowp = &tile[r0 + k + 10][w0 + 4];
        float hv[32];
        #pragma unroll
        for (int q = 0; q < 8; q++) {
            uint2 u = *(const uint2*)(rowp + q * 4);
            up2(u.x, hv[q*4+0], hv[q*4+1]);
            up2(u.y, hv[q*4+2], hv[q*4+3]);
        }
        #pragma unroll
        for (int j = 0; j < 21; j++) {
            float wt = wh[j];
            #pragma unroll
            for (int i = 0; i < 8; i++) acc[k][i] += wt * hv[i + j + 2];
        }
    }

    size_t obase = (size_t)bc * HW;
    #pragma unroll
    for (int k = 0; k < 4; k++) {
        uint4 u;
        u.x = (unsigned)f2bu(acc[k][0]) | ((unsigned)f2bu(acc[k][1]) << 16);
        u.y = (unsigned)f2bu(acc[k][2]) | ((unsigned)f2bu(acc[k][3]) << 16);
        u.z = (unsigned)f2bu(acc[k][4]) | ((unsigned)f2bu(acc[k][5]) << 16);
        u.w = (unsigned)f2bu(acc[k][6]) | ((unsigned)f2bu(acc[k][7]) << 16);
        *(uint4*)(o + obase + (size_t)(h0 + r0 + k) * 256 + w0) = u;
    }
}

// ---------------------------------------------------------------------------
// K3: 1x1 conv (64x64) per pixel, MFMA. D[o][p] = sum_c W[o][c] X[c][p] + b.
// Block = one (b,h) row of 256 px; wave wv owns 64 px, computes all 64 o.
// A-frag = W rows (ds_read_b128), B-frag = X^T rows (8x ds_read_u16, padded).
// which==0 -> Q layout [bh][w][h*8+c']; which==1 -> K same + V [bh][h*8+c'][w].
__global__ __launch_bounds__(256) void k_pw(
        const unsigned short* __restrict__ in1, const unsigned short* __restrict__ in2,
        const float* __restrict__ wpw, const float* __restrict__ bpw,
        unsigned short* __restrict__ Eq, unsigned short* __restrict__ Fk,
        unsigned short* __restrict__ Fv) {
    __shared__ __align__(16) unsigned short Ws[64][72];
    __shared__ __align__(16) unsigned short Xs[64][260];
    __shared__ float sb[64];
    int tid = threadIdx.x;
    for (int i = tid; i < 4096; i += 256) Ws[i >> 6][i & 63] = f2bu(wpw[i]);
    if (tid < 64) sb[tid] = bpw[tid];
    int which = blockIdx.y;
    const unsigned short* in = which ? in2 : in1;
    int bx = blockIdx.x, b = bx >> 8, h = bx & 255;
    const unsigned short* src = in + (size_t)b * 64 * HW + h * 256;
    for (int i = tid; i < 2048; i += 256) {
        int c = i >> 5, ch = i & 31;
        uint4 u = *(const uint4*)(src + (size_t)c * HW + ch * 8);
        *(uint2*)&Xs[c][ch * 8]     = make_uint2(u.x, u.y);
        *(uint2*)&Xs[c][ch * 8 + 4] = make_uint2(u.z, u.w);
    }
    __syncthreads();

    int lane = tid & 63, wv = tid >> 6;
    int rA = lane & 15, g = lane >> 4;
    int p_off = wv * 64;

    f32x4 acc[4][4];
    #pragma unroll
    for (int m = 0; m < 4; m++)
        #pragma unroll
        for (int n = 0; n < 4; n++) acc[m][n] = (f32x4){0.f, 0.f, 0.f, 0.f};

    #pragma unroll
    for (int ks = 0; ks < 2; ks++) {
        int c0 = ks * 32;
        bf16x8 a[4], bb[4];
        #pragma unroll
        for (int m = 0; m < 4; m++)
            a[m] = *(const bf16x8*)&Ws[16 * m + rA][c0 + 8 * g];
        #pragma unroll
        for (int n = 0; n < 4; n++) {
            int p = p_off + 16 * n + rA;
            uint4 bu;
            bu.x = (unsigned)Xs[c0 + 8*g + 0][p] | ((unsigned)Xs[c0 + 8*g + 1][p] << 16);
            bu.y = (unsigned)Xs[c0 + 8*g + 2][p] | ((unsigned)Xs[c0 + 8*g + 3][p] << 16);
            bu.z = (unsigned)Xs[c0 + 8*g + 4][p] | ((unsigned)Xs[c0 + 8*g + 5][p] << 16);
            bu.w = (unsigned)Xs[c0 + 8*g + 6][p] | ((unsigned)Xs[c0 + 8*g + 7][p] << 16);
            bb[n] = *(bf16x8*)&bu;
        }
        #pragma unroll
        for (int m = 0; m < 4; m++)
            #pragma unroll
            for (int n = 0; n < 4; n++)
                acc[m][n] = __builtin_amdgcn_mfma_f32_16x16x32_bf16(a[m], bb[n], acc[m][n], 0, 0, 0);
    }

    unsigned short* dst = which ? Fk : Eq;
    size_t b8 = (size_t)b * 8;
    #pragma unroll
    for (int m = 0; m < 4; m++) {
        int o0 = 16 * m + 4 * g;
        int hd = o0 >> 3, cp = o0 & 7;
        #pragma unroll
        for (int n = 0; n < 4; n++) {
            int p = p_off + 16 * n + rA;       // = w
            ushort4 pk;
            #pragma unroll
            for (int r = 0; r < 4; r++)
                ((unsigned short*)&pk)[r] = f2bu(acc[m][n][r] + sb[o0 + r]);
            *(ushort4*)(dst + ((b8 + hd) * 256 + p) * 2048 + h * 8 + cp) = pk;
            if (which) {
                #pragma unroll
                for (int r = 0; r < 4; r++) {
                    int o = o0 + r;
                    Fv[((b8 + (o >> 3)) * 2048 + h * 8 + (o & 7)) * 256 + p] =
                        ((unsigned short*)&pk)[r];
                }
            }
        }
    }
}

// ---------------------------------------------------------------------------
// K4: inverse L2 norms of Q rows and K rows (1 wave per 2048-elem row).
__global__ __launch_bounds__(256) void k_norm(
        const unsigned short* __restrict__ Eq, const unsigned short* __restrict__ Fk,
        float* __restrict__ invQ, float* __restrict__ invK) {
    int lane = threadIdx.x & 63, wid = threadIdx.x >> 6;
    int row = blockIdx.x * 4 + wid;    // 0..16383
    const unsigned short* src = (row < 8192) ? Eq : Fk;
    int r = row & 8191;
    const unsigned short* p = src + (size_t)r * 2048;
    float s = 0.f;
    #pragma unroll
    for (int it = 0; it < 4; it++) {
        uint4 u = *(const uint4*)(p + it * 512 + lane * 8);
        unsigned vals[4] = {u.x, u.y, u.z, u.w};
        #pragma unroll
        for (int e = 0; e < 4; e++) {
            float lo = b2f((unsigned short)(vals[e] & 0xffffu));
            float hi = b2f((unsigned short)(vals[e] >> 16));
            s += lo * lo + hi * hi;
        }
    }
    #pragma unroll
    for (int m = 1; m < 64; m <<= 1) s += __shfl_xor(s, m, 64);
    if (lane == 0) {
        float inv = 1.f / fmaxf(sqrtf(s), 1e-12f);
        (row < 8192 ? invQ : invK)[r] = inv;
    }
}

// ---------------------------------------------------------------------------
// K5: fused attention per (bh, 32-row tile). MFMA QK^T (scaled by invQ*invK)
// -> LDS softmax -> MFMA PV + Qn epilogue -> out4 in NCHW bf16.
__global__ __launch_bounds__(256) void k_attn(
        const unsigned short* __restrict__ Eq, const unsigned short* __restrict__ Fk,
        const unsigned short* __restrict__ Fv,
        const float* __restrict__ invQ, const float* __restrict__ invK,
        unsigned short* __restrict__ G) {
    __shared__ float Sbuf[32][257];
    __shared__ __align__(16) unsigned short Pbuf[32][264];
    __shared__ float sQ[32];
    __shared__ float sK[256];
    int bx = blockIdx.x;
    int bh = bx >> 3, itile = bx & 7, i0 = itile * 32;
    int b = bh >> 3, hd = bh & 7;
    const unsigned short* Q  = Eq + (size_t)bh * 256 * 2048;
    const unsigned short* Kp = Fk + (size_t)bh * 256 * 2048;
    const unsigned short* Vt = Fv + (size_t)bh * 2048 * 256;
    int tid = threadIdx.x, lane = tid & 63, wid = tid >> 6;
    if (tid < 32) sQ[tid] = invQ[bh * 256 + i0 + tid];
    sK[tid] = invK[bh * 256 + tid];
    __syncthreads();

    int rA = lane & 15, kf = (lane >> 4) * 8;

    f32x4 acc[2][4];
    #pragma unroll
    for (int ib = 0; ib < 2; ib++)
        #pragma unroll
        for (int jb = 0; jb < 4; jb++) acc[ib][jb] = (f32x4){0.f, 0.f, 0.f, 0.f};

    const unsigned short* q0  = Q  + (size_t)(i0 + rA) * 2048 + kf;
    const unsigned short* q1  = q0 + 16 * 2048;
    const unsigned short* kr0 = Kp + (size_t)(wid * 64 + rA) * 2048 + kf;
    for (int k0 = 0; k0 < 2048; k0 += 32) {
        bf16x8 a0 = *(const bf16x8*)(q0 + k0);
        bf16x8 a1 = *(const bf16x8*)(q1 + k0);
        #pragma unroll
        for (int jb = 0; jb < 4; jb++) {
            bf16x8 bb = *(const bf16x8*)(kr0 + (size_t)jb * 16 * 2048 + k0);
            acc[0][jb] = __builtin_amdgcn_mfma_f32_16x16x32_bf16(a0, bb, acc[0][jb], 0, 0, 0);
            acc[1][jb] = __builtin_amdgcn_mfma_f32_16x16x32_bf16(a1, bb, acc[1][jb], 0, 0, 0);
        }
    }
    #pragma unroll
    for (int ib = 0; ib < 2; ib++)
        #pragma unroll
        for (int jb = 0; jb < 4; jb++)
            #pragma unroll
            for (int r = 0; r < 4; r++) {
                int il = ib * 16 + (lane >> 4) * 4 + r;
                int jl = wid * 64 + jb * 16 + rA;
                Sbuf[il][jl] = acc[ib][jb][r] * sQ[il] * sK[jl];
            }
    __syncthreads();

    {
        int r = tid >> 3, sub = tid & 7;
        float m = -1e30f;
        for (int j = sub * 32; j < sub * 32 + 32; j++) m = fmaxf(m, Sbuf[r][j]);
        #pragma unroll
        for (int msk = 1; msk < 8; msk <<= 1) m = fmaxf(m, __shfl_xor(m, msk, 8));
        float s = 0.f;
        for (int j = sub * 32; j < sub * 32 + 32; j++) {
            float e = __expf(Sbuf[r][j] - m);
            Sbuf[r][j] = e;
            s += e;
        }
        #pragma unroll
        for (int msk = 1; msk < 8; msk <<= 1) s += __shfl_xor(s, msk, 8);
        float inv = 1.f / s;
        for (int j = sub * 32; j < sub * 32 + 32; j++) Pbuf[r][j] = f2bu(Sbuf[r][j] * inv);
    }
    __syncthreads();

    bf16x8 pa[2][8];
    #pragma unroll
    for (int ib = 0; ib < 2; ib++)
        #pragma unroll
        for (int ks = 0; ks < 8; ks++)
            pa[ib][ks] = *(const bf16x8*)&Pbuf[ib * 16 + rA][ks * 32 + kf];

    int dbase = wid * 512;
    for (int dt = 0; dt < 32; dt++) {
        int d0 = dbase + dt * 16;
        f32x4 o0 = {0.f, 0.f, 0.f, 0.f}, o1 = {0.f, 0.f, 0.f, 0.f};
        const unsigned short* vb = Vt + (size_t)(d0 + rA) * 256 + kf;
        #pragma unroll
        for (int ks = 0; ks < 8; ks++) {
            bf16x8 bb = *(const bf16x8*)(vb + ks * 32);
            o0 = __builtin_amdgcn_mfma_f32_16x16x32_bf16(pa[0][ks], bb, o0, 0, 0, 0);
            o1 = __builtin_amdgcn_mfma_f32_16x16x32_bf16(pa[1][ks], bb, o1, 0, 0, 0);
        }
        int d = d0 + rA;
        int cpr = d & 7, hh = d >> 3;
        #pragma unroll
        for (int ib = 0; ib < 2; ib++) {
            f32x4 oa = ib ? o1 : o0;
            int ibase = i0 + ib * 16 + (lane >> 4) * 4;
            ushort4 pk;
            #pragma unroll
            for (int r = 0; r < 4; r++) {
                int il = ib * 16 + (lane >> 4) * 4 + r;
                float qv = b2f(Q[(size_t)(i0 + il) * 2048 + d]) * sQ[il];
                ((unsigned short*)&pk)[r] = f2bu(oa[r] + qv);
            }
            *(ushort4*)(G + (size_t)(b * 64 + hd * 8 + cpr) * HW + hh * 256 + ibase) = pk;
        }
    }
}

// ---------------------------------------------------------------------------
// K6: out = PW(out4) + LN(x1) + LN(x2), MFMA for PW, LN recomputed fp32.
// Block = one (b,h) row of 256 px. Thread t computes LN stats for pixel t,
// writes S12 = x1n + x2n (bf16) to LDS; MFMA epilogue adds it.
__global__ __launch_bounds__(256) void k_final(
        const unsigned short* __restrict__ G,
        const float* __restrict__ x1, const float* __restrict__ x2,
        const float* __restrict__ wpw, const float* __restrict__ bpw,
        const float* __restrict__ w1, const float* __restrict__ b1,
        const float* __restrict__ w2, const float* __restrict__ b2,
        float* __restrict__ out) {
    __shared__ __align__(16) unsigned short Ws[64][72];
    __shared__ __align__(16) unsigned short Gs[64][260];
    __shared__ __align__(16) unsigned short S12[64][260];
    __shared__ float sb[64], cw1[64], cb1[64], cw2[64], cb2[64];
    int tid = threadIdx.x;
    for (int i = tid; i < 4096; i += 256) Ws[i >> 6][i & 63] = f2bu(wpw[i]);
    if (tid < 64) {
        sb[tid] = bpw[tid];
        cw1[tid] = w1[tid]; cb1[tid] = b1[tid];
        cw2[tid] = w2[tid]; cb2[tid] = b2[tid];
    }
    int bx = blockIdx.x, b = bx >> 8, h = bx & 255;
    const unsigned short* src = G + (size_t)b * 64 * HW + h * 256;
    for (int i = tid; i < 2048; i += 256) {
        int c = i >> 5, ch = i & 31;
        uint4 u = *(const uint4*)(src + (size_t)c * HW + ch * 8);
        *(uint2*)&Gs[c][ch * 8]     = make_uint2(u.x, u.y);
        *(uint2*)&Gs[c][ch * 8 + 4] = make_uint2(u.z, u.w);
    }
    __syncthreads();   // cw1/cb1 etc ready before stats use them
    {
        size_t pbase = (size_t)b * 64 * HW + h * 256 + tid;
        float v[64]; float s = 0.f;
        #pragma unroll
        for (int c = 0; c < 64; c++) { v[c] = x1[pbase + (size_t)c * HW]; s += v[c]; }
        float mu = s * 0.015625f, s2 = 0.f;
        #pragma unroll
        for (int c = 0; c < 64; c++) { float d = v[c] - mu; s2 += d * d; }
        float rstd = rsqrtf(s2 * 0.015625f + 1e-5f);
        #pragma unroll
        for (int c = 0; c < 64; c++)
            S12[c][tid] = f2bu((v[c] - mu) * rstd * cw1[c] + cb1[c]);
        s = 0.f;
        #pragma unroll
        for (int c = 0; c < 64; c++) { v[c] = x2[pbase + (size_t)c * HW]; s += v[c]; }
        mu = s * 0.015625f; s2 = 0.f;
        #pragma unroll
        for (int c = 0; c < 64; c++) { float d = v[c] - mu; s2 += d * d; }
        rstd = rsqrtf(s2 * 0.015625f + 1e-5f);
        #pragma unroll
        for (int c = 0; c < 64; c++)
            S12[c][tid] = f2bu(b2f(S12[c][tid]) + (v[c] - mu) * rstd * cw2[c] + cb2[c]);
    }
    __syncthreads();

    int lane = tid & 63, wv = tid >> 6;
    int rA = lane & 15, g = lane >> 4;
    int p_off = wv * 64;

    f32x4 acc[4][4];
    #pragma unroll
    for (int m = 0; m < 4; m++)
        #pragma unroll
        for (int n = 0; n < 4; n++) acc[m][n] = (f32x4){0.f, 0.f, 0.f, 0.f};

    #pragma unroll
    for (int ks = 0; ks < 2; ks++) {
        int c0 = ks * 32;
        bf16x8 a[4], bb[4];
        #pragma unroll
        for (int m = 0; m < 4; m++)
            a[m] = *(const bf16x8*)&Ws[16 * m + rA][c0 + 8 * g];
        #pragma unroll
        for (int n = 0; n < 4; n++) {
            int p = p_off + 16 * n + rA;
            uint4 bu;
            bu.x = (unsigned)Gs[c0 + 8*g + 0][p] | ((unsigned)Gs[c0 + 8*g + 1][p] << 16);
            bu.y = (unsigned)Gs[c0 + 8*g + 2][p] | ((unsigned)Gs[c0 + 8*g + 3][p] << 16);
            bu.z = (unsigned)Gs[c0 + 8*g + 4][p] | ((unsigned)Gs[c0 + 8*g + 5][p] << 16);
            bu.w = (unsigned)Gs[c0 + 8*g + 6][p] | ((unsigned)Gs[c0 + 8*g + 7][p] << 16);
            bb[n] = *(bf16x8*)&bu;
        }
        #pragma unroll
        for (int m = 0; m < 4; m++)
            #pragma unroll
            for (int n = 0; n < 4; n++)
                acc[m][n] = __builtin_amdgcn_mfma_f32_16x16x32_bf16(a[m], bb[n], acc[m][n], 0, 0, 0);
    }

    #pragma unroll
    for (int m = 0; m < 4; m++) {
        int o0 = 16 * m + 4 * g;
        #pragma unroll
        for (int n = 0; n < 4; n++) {
            int p = p_off + 16 * n + rA;
            #pragma unroll
            for (int r = 0; r < 4; r++) {
                int o = o0 + r;
                out[(size_t)(b * 64 + o) * HW + h * 256 + p] =
                    acc[m][n][r] + sb[o] + b2f(S12[o][p]);
            }
        }
    }
}

// ---------------------------------------------------------------------------
extern "C" void kernel_launch(void* const* d_in, const int* in_sizes, int n_in,
                              void* d_out, int out_size, void* d_ws, size_t ws_size,
                              hipStream_t stream) {
    const float* x1   = (const float*)d_in[0];
    const float* x2   = (const float*)d_in[1];
    const float* ln1w = (const float*)d_in[2];
    const float* ln1b = (const float*)d_in[3];
    const float* ln2w = (const float*)d_in[4];
    const float* ln2b = (const float*)d_in[5];
    const float* bdw  = (const float*)d_in[6];
    const float* wpw  = (const float*)d_in[7];
    const float* bpw  = (const float*)d_in[8];
    const float* kk[12];
    for (int i = 0; i < 12; i++) kk[i] = (const float*)d_in[9 + i];

    char* ws = (char*)d_ws;
    float* wcomb = (float*)ws;              // 5376 floats
    float* bias  = (float*)(ws + 21504);    // 128 floats
    float* invQ  = (float*)(ws + 32768);    // 8192 floats
    float* invK  = (float*)(ws + 65536);    // 8192 floats
    const size_t SMALL = 131072;
    const size_t SZ = 33554432;             // 32 MiB = 16.7M bf16 elements

    // Slots: A = x1n -> Q, B = x2n -> K, C = V, D = out4 (all in ws).
    // dw1/dw2 live in d_out (64 MiB, dead before k_final overwrites it).
    unsigned short* A = (unsigned short*)(ws + SMALL);
    unsigned short* B = (unsigned short*)(ws + SMALL + SZ);
    unsigned short* C = (unsigned short*)(ws + SMALL + 2 * SZ);
    unsigned short* D = (unsigned short*)(ws + SMALL + 3 * SZ);
    unsigned short* dw1 = (unsigned short*)d_out;
    unsigned short* dw2 = dw1 + SZ / 2;     // element offset = 16.7M

    k_prep<<<1, 64, 0, stream>>>(kk[0], kk[1], kk[2], kk[3], kk[4], kk[5],
                                 kk[6], kk[7], kk[8], kk[9], kk[10], kk[11],
                                 bdw, wcomb, bias);
    k_ln<<<dim3(1024, 2), 256, 0, stream>>>(x1, x2, ln1w, ln1b, ln2w, ln2b, A, B);
    k_dw<<<dim3(2048, 2), 256, 0, stream>>>(A, B, wcomb, bias, dw1, dw2);
    k_pw<<<dim3(1024, 2), 256, 0, stream>>>(dw1, dw2, wpw, bpw, A, B, C);
    k_norm<<<4096, 256, 0, stream>>>(A, B, invQ, invK);
    k_attn<<<256, 256, 0, stream>>>(A, B, C, invQ, invK, D);
    k_final<<<1024, 256, 0, stream>>>(D, x1, x2, wpw, bpw,
                                      ln1w, ln1b, ln2w, ln2b, (float*)d_out);
}

// Round 4
// 353.067 us; speedup vs baseline: 3.3425x; 1.0064x over previous
//
#include <hip/hip_runtime.h>

#define HW 65536  // 256*256

typedef __bf16 bf16x8 __attribute__((ext_vector_type(8)));
typedef float f32x4 __attribute__((ext_vector_type(4)));

__device__ __forceinline__ float b2f(unsigned short u) {
    return __uint_as_float(((unsigned)u) << 16);
}
__device__ __forceinline__ unsigned short f2bu(float f) {
    unsigned u = __float_as_uint(f);
    return (unsigned short)((u + 0x7FFFu + ((u >> 16) & 1u)) >> 16);
}
// unpack a u32 holding 2 bf16 -> 2 floats (1 VALU op each)
__device__ __forceinline__ void up2(unsigned u, float& lo, float& hi) {
    lo = __uint_as_float(u << 16);
    hi = __uint_as_float(u & 0xFFFF0000u);
}

// ---------------------------------------------------------------------------
// K0: fold 6 depthwise kernels -> combined 21-tap h + 21-tap v per tensor,
// and sum the 6 biases per tensor. wcomb layout: wh1|wv1|wh2|wv2, each 64*21.
__global__ void k_prep(const float* k11, const float* k12, const float* k13,
                       const float* k14, const float* k15, const float* k16,
                       const float* k21, const float* k22, const float* k23,
                       const float* k24, const float* k25, const float* k26,
                       const float* bdw, float* wcomb, float* bias) {
    int c = threadIdx.x;
    if (c >= 64) return;
    float* wh1 = wcomb;
    float* wv1 = wcomb + 1344;
    float* wh2 = wcomb + 2688;
    float* wv2 = wcomb + 4032;
    for (int j = 0; j < 21; j++) {
        wh1[c*21+j] = k13[c*21+j];
        wv1[c*21+j] = k16[c*21+j];
        wh2[c*21+j] = k23[c*21+j];
        wv2[c*21+j] = k26[c*21+j];
    }
    for (int j = 0; j < 11; j++) {
        wh1[c*21+j+5] += k12[c*11+j];
        wv1[c*21+j+5] += k15[c*11+j];
        wh2[c*21+j+5] += k22[c*11+j];
        wv2[c*21+j+5] += k25[c*11+j];
    }
    for (int j = 0; j < 7; j++) {
        wh1[c*21+j+7] += k11[c*7+j];
        wv1[c*21+j+7] += k14[c*7+j];
        wh2[c*21+j+7] += k21[c*7+j];
        wv2[c*21+j+7] += k24[c*7+j];
    }
    float s1 = 0.f, s2 = 0.f;
    for (int i = 0; i < 6; i++) { s1 += bdw[i*64+c]; s2 += bdw[(6+i)*64+c]; }
    bias[c] = s1; bias[64+c] = s2;
}

// ---------------------------------------------------------------------------
// K1: per-pixel LayerNorm over 64 channels, fp32 in -> bf16 out (NCHW).
__global__ __launch_bounds__(256) void k_ln(
        const float* __restrict__ x1, const float* __restrict__ x2,
        const float* __restrict__ w1, const float* __restrict__ b1,
        const float* __restrict__ w2, const float* __restrict__ b2,
        unsigned short* __restrict__ o1, unsigned short* __restrict__ o2) {
    int which = blockIdx.y;
    const float* x  = which ? x2 : x1;
    const float* lw = which ? w2 : w1;
    const float* lb = which ? b2 : b1;
    unsigned short* o = which ? o2 : o1;
    int p = blockIdx.x * 256 + threadIdx.x;   // 0..262143
    int b = p >> 16, hw = p & (HW - 1);
    size_t base = (size_t)b * 64 * HW + hw;
    float v[64];
    float s = 0.f;
    #pragma unroll
    for (int c = 0; c < 64; c++) { v[c] = x[base + (size_t)c * HW]; s += v[c]; }
    float mu = s * 0.015625f;
    float s2 = 0.f;
    #pragma unroll
    for (int c = 0; c < 64; c++) { float d = v[c] - mu; s2 += d * d; }
    float rstd = rsqrtf(s2 * 0.015625f + 1e-5f);
    #pragma unroll
    for (int c = 0; c < 64; c++)
        o[base + (size_t)c * HW] = f2bu((v[c] - mu) * rstd * lw[c] + lb[c]);
}

// ---------------------------------------------------------------------------
// K2: combined depthwise conv (21-tap h + 21-tap v + bias), LDS-tiled.
__global__ __launch_bounds__(256) void k_dw(
        const unsigned short* __restrict__ in1, const unsigned short* __restrict__ in2,
        const float* __restrict__ wcomb, const float* __restrict__ bias,
        unsigned short* __restrict__ o1, unsigned short* __restrict__ o2) {
    __shared__ __align__(16) unsigned short tile[52][288];
    int which = blockIdx.y;
    const unsigned short* in = which ? in2 : in1;
    unsigned short* o = which ? o2 : o1;
    int bx = blockIdx.x;               // bc*8 + tileid
    int bc = bx >> 3, tileid = bx & 7;
    int c = bc & 63;
    int h0 = tileid * 32;
    const float* whp = wcomb + which * 2688 + c * 21;
    const float* wvp = whp + 1344;
    float wh[21], wv[21];
    #pragma unroll
    for (int j = 0; j < 21; j++) { wh[j] = whp[j]; wv[j] = wvp[j]; }
    float bs = bias[which * 64 + c];
    const unsigned short* src = in + (size_t)bc * HW;
    int tid = threadIdx.x;

    // stage 52 rows x 36 chunks (8 bf16 each); chunks 0,1,34,35 are zero pads
    for (int idx = tid; idx < 52 * 36; idx += 256) {
        int row = idx / 36, chunk = idx - row * 36;
        int grow = h0 - 10 + row;
        uint4 val = make_uint4(0u, 0u, 0u, 0u);
        if ((unsigned)grow < 256u && chunk >= 2 && chunk <= 33)
            val = *(const uint4*)(src + grow * 256 + (chunk - 2) * 8);
        *(uint4*)&tile[row][chunk * 8] = val;
    }
    __syncthreads();

    int seg = tid & 31, rgrp = tid >> 5;
    int w0 = seg * 8;
    int r0 = rgrp * 4;

    float acc[4][8];
    #pragma unroll
    for (int k = 0; k < 4; k++)
        #pragma unroll
        for (int i = 0; i < 8; i++) acc[k][i] = bs;

    #pragma unroll
    for (int rr = 0; rr < 24; rr++) {
        uint4 u = *(const uint4*)&tile[r0 + rr][16 + w0];
        float v[8];
        up2(u.x, v[0], v[1]); up2(u.y, v[2], v[3]);
        up2(u.z, v[4], v[5]); up2(u.w, v[6], v[7]);
        #pragma unroll
        for (int k = 0; k < 4; k++) {
            const int j = rr - k;
            if (j >= 0 && j < 21) {
                float wt = wv[j];
                #pragma unroll
                for (int i = 0; i < 8; i++) acc[k][i] += wt * v[i];
            }
        }
    }

    #pragma unroll
    for (int k = 0; k < 4; k++) {
        const unsigned short* rowp = &tile[r0 + k + 10][w0 + 4];
        float hv[32];
        #pragma unroll
        for (int q = 0; q < 8; q++) {
            uint2 u = *(const uint2*)(rowp + q * 4);
            up2(u.x, hv[q*4+0], hv[q*4+1]);
            up2(u.y, hv[q*4+2], hv[q*4+3]);
        }
        #pragma unroll
        for (int j = 0; j < 21; j++) {
            float wt = wh[j];
            #pragma unroll
            for (int i = 0; i < 8; i++) acc[k][i] += wt * hv[i + j + 2];
        }
    }

    size_t obase = (size_t)bc * HW;
    #pragma unroll
    for (int k = 0; k < 4; k++) {
        uint4 u;
        u.x = (unsigned)f2bu(acc[k][0]) | ((unsigned)f2bu(acc[k][1]) << 16);
        u.y = (unsigned)f2bu(acc[k][2]) | ((unsigned)f2bu(acc[k][3]) << 16);
        u.z = (unsigned)f2bu(acc[k][4]) | ((unsigned)f2bu(acc[k][5]) << 16);
        u.w = (unsigned)f2bu(acc[k][6]) | ((unsigned)f2bu(acc[k][7]) << 16);
        *(uint4*)(o + obase + (size_t)(h0 + r0 + k) * 256 + w0) = u;
    }
}

// ---------------------------------------------------------------------------
// K3: 1x1 conv (64x64) per pixel, MFMA. D[o][p] = sum_c W[o][c] X[c][p] + b.
__global__ __launch_bounds__(256) void k_pw(
        const unsigned short* __restrict__ in1, const unsigned short* __restrict__ in2,
        const float* __restrict__ wpw, const float* __restrict__ bpw,
        unsigned short* __restrict__ Eq, unsigned short* __restrict__ Fk,
        unsigned short* __restrict__ Fv) {
    __shared__ __align__(16) unsigned short Ws[64][72];
    __shared__ __align__(16) unsigned short Xs[64][260];
    __shared__ float sb[64];
    int tid = threadIdx.x;
    for (int i = tid; i < 4096; i += 256) Ws[i >> 6][i & 63] = f2bu(wpw[i]);
    if (tid < 64) sb[tid] = bpw[tid];
    int which = blockIdx.y;
    const unsigned short* in = which ? in2 : in1;
    int bx = blockIdx.x, b = bx >> 8, h = bx & 255;
    const unsigned short* src = in + (size_t)b * 64 * HW + h * 256;
    for (int i = tid; i < 2048; i += 256) {
        int c = i >> 5, ch = i & 31;
        uint4 u = *(const uint4*)(src + (size_t)c * HW + ch * 8);
        *(uint2*)&Xs[c][ch * 8]     = make_uint2(u.x, u.y);
        *(uint2*)&Xs[c][ch * 8 + 4] = make_uint2(u.z, u.w);
    }
    __syncthreads();

    int lane = tid & 63, wv = tid >> 6;
    int rA = lane & 15, g = lane >> 4;
    int p_off = wv * 64;

    f32x4 acc[4][4];
    #pragma unroll
    for (int m = 0; m < 4; m++)
        #pragma unroll
        for (int n = 0; n < 4; n++) acc[m][n] = (f32x4){0.f, 0.f, 0.f, 0.f};

    #pragma unroll
    for (int ks = 0; ks < 2; ks++) {
        int c0 = ks * 32;
        bf16x8 a[4], bb[4];
        #pragma unroll
        for (int m = 0; m < 4; m++)
            a[m] = *(const bf16x8*)&Ws[16 * m + rA][c0 + 8 * g];
        #pragma unroll
        for (int n = 0; n < 4; n++) {
            int p = p_off + 16 * n + rA;
            uint4 bu;
            bu.x = (unsigned)Xs[c0 + 8*g + 0][p] | ((unsigned)Xs[c0 + 8*g + 1][p] << 16);
            bu.y = (unsigned)Xs[c0 + 8*g + 2][p] | ((unsigned)Xs[c0 + 8*g + 3][p] << 16);
            bu.z = (unsigned)Xs[c0 + 8*g + 4][p] | ((unsigned)Xs[c0 + 8*g + 5][p] << 16);
            bu.w = (unsigned)Xs[c0 + 8*g + 6][p] | ((unsigned)Xs[c0 + 8*g + 7][p] << 16);
            bb[n] = *(bf16x8*)&bu;
        }
        #pragma unroll
        for (int m = 0; m < 4; m++)
            #pragma unroll
            for (int n = 0; n < 4; n++)
                acc[m][n] = __builtin_amdgcn_mfma_f32_16x16x32_bf16(a[m], bb[n], acc[m][n], 0, 0, 0);
    }

    unsigned short* dst = which ? Fk : Eq;
    size_t b8 = (size_t)b * 8;
    #pragma unroll
    for (int m = 0; m < 4; m++) {
        int o0 = 16 * m + 4 * g;
        int hd = o0 >> 3, cp = o0 & 7;
        #pragma unroll
        for (int n = 0; n < 4; n++) {
            int p = p_off + 16 * n + rA;       // = w
            ushort4 pk;
            #pragma unroll
            for (int r = 0; r < 4; r++)
                ((unsigned short*)&pk)[r] = f2bu(acc[m][n][r] + sb[o0 + r]);
            *(ushort4*)(dst + ((b8 + hd) * 256 + p) * 2048 + h * 8 + cp) = pk;
            if (which) {
                #pragma unroll
                for (int r = 0; r < 4; r++) {
                    int o = o0 + r;
                    Fv[((b8 + (o >> 3)) * 2048 + h * 8 + (o & 7)) * 256 + p] =
                        ((unsigned short*)&pk)[r];
                }
            }
        }
    }
}

// ---------------------------------------------------------------------------
// K4: inverse L2 norms of Q rows and K rows (1 wave per 2048-elem row).
__global__ __launch_bounds__(256) void k_norm(
        const unsigned short* __restrict__ Eq, const unsigned short* __restrict__ Fk,
        float* __restrict__ invQ, float* __restrict__ invK) {
    int lane = threadIdx.x & 63, wid = threadIdx.x >> 6;
    int row = blockIdx.x * 4 + wid;    // 0..16383
    const unsigned short* src = (row < 8192) ? Eq : Fk;
    int r = row & 8191;
    const unsigned short* p = src + (size_t)r * 2048;
    float s = 0.f;
    #pragma unroll
    for (int it = 0; it < 4; it++) {
        uint4 u = *(const uint4*)(p + it * 512 + lane * 8);
        unsigned vals[4] = {u.x, u.y, u.z, u.w};
        #pragma unroll
        for (int e = 0; e < 4; e++) {
            float lo = b2f((unsigned short)(vals[e] & 0xffffu));
            float hi = b2f((unsigned short)(vals[e] >> 16));
            s += lo * lo + hi * hi;
        }
    }
    #pragma unroll
    for (int m = 1; m < 64; m <<= 1) s += __shfl_xor(s, m, 64);
    if (lane == 0) {
        float inv = 1.f / fmaxf(sqrtf(s), 1e-12f);
        (row < 8192 ? invQ : invK)[r] = inv;
    }
}

// ---------------------------------------------------------------------------
// K5: fused attention. Grid 256 = (tile 0..7) * 32 + bh, so all 8 tiles of a
// bh land on XCD bh%8 (round-robin) -> K/V HBM-read once, L2 serves re-reads.
// 512 threads = 8 waves: QK^T waves split S-cols (32 each); PV waves split
// d (256 each). Softmax 16 thr/row col-strided (Sbuf stride 264, 2-way max).
// Pbuf [32][256] bf16 with 16B-unit XOR swizzle (unit ^= row&7): conflict-
// free ds_read_b128 fragment loads.
__global__ __launch_bounds__(512) void k_attn(
        const unsigned short* __restrict__ Eq, const unsigned short* __restrict__ Fk,
        const unsigned short* __restrict__ Fv,
        const float* __restrict__ invQ, const float* __restrict__ invK,
        unsigned short* __restrict__ G) {
    __shared__ float Sbuf[32][264];
    __shared__ __align__(16) unsigned short Pbuf[32][256];
    __shared__ float sQ[32];
    __shared__ float sK[256];
    int bx = blockIdx.x;
    int bh = bx & 31, itile = bx >> 5, i0 = itile * 32;
    int b = bh >> 3, hd = bh & 7;
    const unsigned short* Q  = Eq + (size_t)bh * 256 * 2048;
    const unsigned short* Kp = Fk + (size_t)bh * 256 * 2048;
    const unsigned short* Vt = Fv + (size_t)bh * 2048 * 256;
    int tid = threadIdx.x, lane = tid & 63, wid = tid >> 6;
    if (tid < 32) sQ[tid] = invQ[bh * 256 + i0 + tid];
    if (tid < 256) sK[tid] = invK[bh * 256 + tid];
    __syncthreads();

    int rA = lane & 15, g = lane >> 4, kf = g * 8;

    // ---- QK^T: wave wid owns S cols [wid*32, wid*32+32) ----
    f32x4 acc[2][2];
    #pragma unroll
    for (int ib = 0; ib < 2; ib++)
        #pragma unroll
        for (int jb = 0; jb < 2; jb++) acc[ib][jb] = (f32x4){0.f, 0.f, 0.f, 0.f};

    const unsigned short* q0  = Q  + (size_t)(i0 + rA) * 2048 + kf;
    const unsigned short* q1  = q0 + 16 * 2048;
    const unsigned short* kr0 = Kp + (size_t)(wid * 32 + rA) * 2048 + kf;
    for (int k0 = 0; k0 < 2048; k0 += 32) {
        bf16x8 a0 = *(const bf16x8*)(q0 + k0);
        bf16x8 a1 = *(const bf16x8*)(q1 + k0);
        #pragma unroll
        for (int jb = 0; jb < 2; jb++) {
            bf16x8 bb = *(const bf16x8*)(kr0 + (size_t)jb * 16 * 2048 + k0);
            acc[0][jb] = __builtin_amdgcn_mfma_f32_16x16x32_bf16(a0, bb, acc[0][jb], 0, 0, 0);
            acc[1][jb] = __builtin_amdgcn_mfma_f32_16x16x32_bf16(a1, bb, acc[1][jb], 0, 0, 0);
        }
    }
    #pragma unroll
    for (int ib = 0; ib < 2; ib++)
        #pragma unroll
        for (int jb = 0; jb < 2; jb++)
            #pragma unroll
            for (int r = 0; r < 4; r++) {
                int il = ib * 16 + g * 4 + r;
                int jl = wid * 32 + jb * 16 + rA;
                Sbuf[il][jl] = acc[ib][jb][r] * sQ[il] * sK[jl];
            }
    __syncthreads();

    // ---- softmax: 16 threads/row, col-strided; exp vals kept in regs ----
    {
        int r = tid >> 4, sub = tid & 15;
        float ev[16];
        float m = -1e30f;
        #pragma unroll
        for (int j = 0; j < 16; j++) {
            ev[j] = Sbuf[r][sub + 16 * j];
            m = fmaxf(m, ev[j]);
        }
        #pragma unroll
        for (int msk = 1; msk < 16; msk <<= 1) m = fmaxf(m, __shfl_xor(m, msk, 16));
        float s = 0.f;
        #pragma unroll
        for (int j = 0; j < 16; j++) { ev[j] = __expf(ev[j] - m); s += ev[j]; }
        #pragma unroll
        for (int msk = 1; msk < 16; msk <<= 1) s += __shfl_xor(s, msk, 16);
        float inv = 1.f / s;
        #pragma unroll
        for (int j = 0; j < 16; j++) {
            int c = sub + 16 * j;
            int unit = (c >> 3) ^ (r & 7);
            Pbuf[r][unit * 8 + (c & 7)] = f2bu(ev[j] * inv);
        }
    }
    __syncthreads();

    // ---- PV + Qn, write NCHW; wave wid owns d in [wid*256, wid*256+256) ----
    bf16x8 pa[2][8];
    #pragma unroll
    for (int ib = 0; ib < 2; ib++)
        #pragma unroll
        for (int ks = 0; ks < 8; ks++) {
            int rr = ib * 16 + rA;
            int unit = (ks * 4 + g) ^ (rr & 7);
            pa[ib][ks] = *(const bf16x8*)&Pbuf[rr][unit * 8];
        }

    int dbase = wid * 256;
    for (int dt = 0; dt < 16; dt++) {
        int d0 = dbase + dt * 16;
        f32x4 o0 = {0.f, 0.f, 0.f, 0.f}, o1 = {0.f, 0.f, 0.f, 0.f};
        const unsigned short* vb = Vt + (size_t)(d0 + rA) * 256 + kf;
        #pragma unroll
        for (int ks = 0; ks < 8; ks++) {
            bf16x8 bb = *(const bf16x8*)(vb + ks * 32);
            o0 = __builtin_amdgcn_mfma_f32_16x16x32_bf16(pa[0][ks], bb, o0, 0, 0, 0);
            o1 = __builtin_amdgcn_mfma_f32_16x16x32_bf16(pa[1][ks], bb, o1, 0, 0, 0);
        }
        int d = d0 + rA;
        int cpr = d & 7, hh = d >> 3;
        #pragma unroll
        for (int ib = 0; ib < 2; ib++) {
            f32x4 oa = ib ? o1 : o0;
            int ibase = i0 + ib * 16 + g * 4;
            ushort4 pk;
            #pragma unroll
            for (int r = 0; r < 4; r++) {
                int il = ib * 16 + g * 4 + r;
                float qv = b2f(Q[(size_t)(i0 + il) * 2048 + d]) * sQ[il];
                ((unsigned short*)&pk)[r] = f2bu(oa[r] + qv);
            }
            *(ushort4*)(G + (size_t)(b * 64 + hd * 8 + cpr) * HW + hh * 256 + ibase) = pk;
        }
    }
}

// ---------------------------------------------------------------------------
// K6: out = PW(out4) + LN(x1) + LN(x2), MFMA for PW, LN recomputed fp32.
__global__ __launch_bounds__(256) void k_final(
        const unsigned short* __restrict__ G,
        const float* __restrict__ x1, const float* __restrict__ x2,
        const float* __restrict__ wpw, const float* __restrict__ bpw,
        const float* __restrict__ w1, const float* __restrict__ b1,
        const float* __restrict__ w2, const float* __restrict__ b2,
        float* __restrict__ out) {
    __shared__ __align__(16) unsigned short Ws[64][72];
    __shared__ __align__(16) unsigned short Gs[64][260];
    __shared__ __align__(16) unsigned short S12[64][260];
    __shared__ float sb[64], cw1[64], cb1[64], cw2[64], cb2[64];
    int tid = threadIdx.x;
    for (int i = tid; i < 4096; i += 256) Ws[i >> 6][i & 63] = f2bu(wpw[i]);
    if (tid < 64) {
        sb[tid] = bpw[tid];
        cw1[tid] = w1[tid]; cb1[tid] = b1[tid];
        cw2[tid] = w2[tid]; cb2[tid] = b2[tid];
    }
    int bx = blockIdx.x, b = bx >> 8, h = bx & 255;
    const unsigned short* src = G + (size_t)b * 64 * HW + h * 256;
    for (int i = tid; i < 2048; i += 256) {
        int c = i >> 5, ch = i & 31;
        uint4 u = *(const uint4*)(src + (size_t)c * HW + ch * 8);
        *(uint2*)&Gs[c][ch * 8]     = make_uint2(u.x, u.y);
        *(uint2*)&Gs[c][ch * 8 + 4] = make_uint2(u.z, u.w);
    }
    __syncthreads();   // cw1/cb1 etc ready before stats use them
    {
        size_t pbase = (size_t)b * 64 * HW + h * 256 + tid;
        float v[64]; float s = 0.f;
        #pragma unroll
        for (int c = 0; c < 64; c++) { v[c] = x1[pbase + (size_t)c * HW]; s += v[c]; }
        float mu = s * 0.015625f, s2 = 0.f;
        #pragma unroll
        for (int c = 0; c < 64; c++) { float d = v[c] - mu; s2 += d * d; }
        float rstd = rsqrtf(s2 * 0.015625f + 1e-5f);
        #pragma unroll
        for (int c = 0; c < 64; c++)
            S12[c][tid] = f2bu((v[c] - mu) * rstd * cw1[c] + cb1[c]);
        s = 0.f;
        #pragma unroll
        for (int c = 0; c < 64; c++) { v[c] = x2[pbase + (size_t)c * HW]; s += v[c]; }
        mu = s * 0.015625f; s2 = 0.f;
        #pragma unroll
        for (int c = 0; c < 64; c++) { float d = v[c] - mu; s2 += d * d; }
        rstd = rsqrtf(s2 * 0.015625f + 1e-5f);
        #pragma unroll
        for (int c = 0; c < 64; c++)
            S12[c][tid] = f2bu(b2f(S12[c][tid]) + (v[c] - mu) * rstd * cw2[c] + cb2[c]);
    }
    __syncthreads();

    int lane = tid & 63, wv = tid >> 6;
    int rA = lane & 15, g = lane >> 4;
    int p_off = wv * 64;

    f32x4 acc[4][4];
    #pragma unroll
    for (int m = 0; m < 4; m++)
        #pragma unroll
        for (int n = 0; n < 4; n++) acc[m][n] = (f32x4){0.f, 0.f, 0.f, 0.f};

    #pragma unroll
    for (int ks = 0; ks < 2; ks++) {
        int c0 = ks * 32;
        bf16x8 a[4], bb[4];
        #pragma unroll
        for (int m = 0; m < 4; m++)
            a[m] = *(const bf16x8*)&Ws[16 * m + rA][c0 + 8 * g];
        #pragma unroll
        for (int n = 0; n < 4; n++) {
            int p = p_off + 16 * n + rA;
            uint4 bu;
            bu.x = (unsigned)Gs[c0 + 8*g + 0][p] | ((unsigned)Gs[c0 + 8*g + 1][p] << 16);
            bu.y = (unsigned)Gs[c0 + 8*g + 2][p] | ((unsigned)Gs[c0 + 8*g + 3][p] << 16);
            bu.z = (unsigned)Gs[c0 + 8*g + 4][p] | ((unsigned)Gs[c0 + 8*g + 5][p] << 16);
            bu.w = (unsigned)Gs[c0 + 8*g + 6][p] | ((unsigned)Gs[c0 + 8*g + 7][p] << 16);
            bb[n] = *(bf16x8*)&bu;
        }
        #pragma unroll
        for (int m = 0; m < 4; m++)
            #pragma unroll
            for (int n = 0; n < 4; n++)
                acc[m][n] = __builtin_amdgcn_mfma_f32_16x16x32_bf16(a[m], bb[n], acc[m][n], 0, 0, 0);
    }

    #pragma unroll
    for (int m = 0; m < 4; m++) {
        int o0 = 16 * m + 4 * g;
        #pragma unroll
        for (int n = 0; n < 4; n++) {
            int p = p_off + 16 * n + rA;
            #pragma unroll
            for (int r = 0; r < 4; r++) {
                int o = o0 + r;
                out[(size_t)(b * 64 + o) * HW + h * 256 + p] =
                    acc[m][n][r] + sb[o] + b2f(S12[o][p]);
            }
        }
    }
}

// ---------------------------------------------------------------------------
extern "C" void kernel_launch(void* const* d_in, const int* in_sizes, int n_in,
                              void* d_out, int out_size, void* d_ws, size_t ws_size,
                              hipStream_t stream) {
    const float* x1   = (const float*)d_in[0];
    const float* x2   = (const float*)d_in[1];
    const float* ln1w = (const float*)d_in[2];
    const float* ln1b = (const float*)d_in[3];
    const float* ln2w = (const float*)d_in[4];
    const float* ln2b = (const float*)d_in[5];
    const float* bdw  = (const float*)d_in[6];
    const float* wpw  = (const float*)d_in[7];
    const float* bpw  = (const float*)d_in[8];
    const float* kk[12];
    for (int i = 0; i < 12; i++) kk[i] = (const float*)d_in[9 + i];

    char* ws = (char*)d_ws;
    float* wcomb = (float*)ws;              // 5376 floats
    float* bias  = (float*)(ws + 21504);    // 128 floats
    float* invQ  = (float*)(ws + 32768);    // 8192 floats
    float* invK  = (float*)(ws + 65536);    // 8192 floats
    const size_t SMALL = 131072;
    const size_t SZ = 33554432;             // 32 MiB = 16.7M bf16 elements

    // Slots: A = x1n -> Q, B = x2n -> K, C = V, D = out4 (all in ws).
    // dw1/dw2 live in d_out (64 MiB, dead before k_final overwrites it).
    unsigned short* A = (unsigned short*)(ws + SMALL);
    unsigned short* B = (unsigned short*)(ws + SMALL + SZ);
    unsigned short* C = (unsigned short*)(ws + SMALL + 2 * SZ);
    unsigned short* D = (unsigned short*)(ws + SMALL + 3 * SZ);
    unsigned short* dw1 = (unsigned short*)d_out;
    unsigned short* dw2 = dw1 + SZ / 2;     // element offset = 16.7M

    k_prep<<<1, 64, 0, stream>>>(kk[0], kk[1], kk[2], kk[3], kk[4], kk[5],
                                 kk[6], kk[7], kk[8], kk[9], kk[10], kk[11],
                                 bdw, wcomb, bias);
    k_ln<<<dim3(1024, 2), 256, 0, stream>>>(x1, x2, ln1w, ln1b, ln2w, ln2b, A, B);
    k_dw<<<dim3(2048, 2), 256, 0, stream>>>(A, B, wcomb, bias, dw1, dw2);
    k_pw<<<dim3(1024, 2), 256, 0, stream>>>(dw1, dw2, wpw, bpw, A, B, C);
    k_norm<<<4096, 256, 0, stream>>>(A, B, invQ, invK);
    k_attn<<<256, 512, 0, stream>>>(A, B, C, invQ, invK, D);
    k_final<<<1024, 256, 0, stream>>>(D, x1, x2, wpw, bpw,
                                      ln1w, ln1b, ln2w, ln2b, (float*)d_out);
}